// Round 1
// baseline (2846.627 us; speedup 1.0000x reference)
//
#include <hip/hip_runtime.h>
#include <stdint.h>
#include <stddef.h>

#define NCH   256
#define EDIM  64
#define HDIM  128
#define G3    384
#define BATCH 128
#define WRD   64
#define CLEN  48
#define NW    8192
#define OUTD  8
#define SPB   8

// ---- canonical fp32 weight offsets (element units) ----
#define C_EMB     0
#define C_CWIH_F  16384
#define C_CWHH_F  40960
#define C_CBIH_F  90112
#define C_CBHH_F  90496
#define C_CWIH_B  90880
#define C_CWHH_B  115456
#define C_CBIH_B  164608
#define C_CBHH_B  164992
#define C_MWIH_F  165376
#define C_MWHH_F  263680
#define C_MBIH_F  312832
#define C_MBHH_F  313600
#define C_MWIH_B  314368
#define C_MWHH_B  412672
#define C_MBIH_B  461824
#define C_MBHH_B  462592
#define C_WWP     463360
#define C_WBP     496128
#define C_WCTX    496256
#define C_PWP     496384
#define C_PBP     529152
#define C_PCTX    529280
#define C_WOUT    529408
#define C_BOUT    531456
#define C_TOTAL   531464

// ---- ws byte offsets ----
#define OFF_FLAG    0u
#define OFF_CANON   1024u
#define OFF_WPT2_W  (4u*1024u*1024u)
#define OFF_WPT2_P  (4u*1024u*1024u + 65536u)
#define OFF_MWIHT   (4u*1024u*1024u + 131072u)
#define OFF_XGM     (8u*1024u*1024u)          // 2*8192*384*4 = 25,165,824
#define OFF_WORDS   35651584u                  // 8192*256*4 = 8,388,608
#define OFF_MSGOUT  47185920u                  // 128*64*256*2 = 4,194,304
#define OFF_CHOUT   54525952u                  // 8192*48*256*2 = 201,326,592

typedef _Float16 h2v __attribute__((ext_vector_type(2)));

__device__ __forceinline__ float bf16_to_f32(unsigned short u){
  union{unsigned int i;float f;}v; v.i=((unsigned int)u)<<16; return v.f;
}
__device__ __forceinline__ unsigned short f32_to_bf16(float f){
  union{float f;unsigned int i;}v; v.f=f;
  unsigned int u=v.i; unsigned int r=(u + 0x7fffu + ((u>>16)&1u))>>16;
  return (unsigned short)r;
}
__device__ __forceinline__ uint32_t pack_h2(float x,float y){
  h2v h; h[0]=(_Float16)x; h[1]=(_Float16)y; uint32_t u; __builtin_memcpy(&u,&h,4); return u;
}
__device__ __forceinline__ unsigned short f32_to_h16u(float f){
  _Float16 h=(_Float16)f; unsigned short u; __builtin_memcpy(&u,&h,2); return u;
}
__device__ __forceinline__ float h16lo(uint32_t u){
  unsigned short s=(unsigned short)(u&0xffffu); _Float16 h; __builtin_memcpy(&h,&s,2); return (float)h;
}
__device__ __forceinline__ float h16hi(uint32_t u){
  unsigned short s=(unsigned short)(u>>16); _Float16 h; __builtin_memcpy(&h,&s,2); return (float)h;
}
__device__ __forceinline__ float dot2(uint32_t a, uint32_t b, float c){
#if __has_builtin(__builtin_amdgcn_fdot2)
  h2v av,bv; __builtin_memcpy(&av,&a,4); __builtin_memcpy(&bv,&b,4);
  return __builtin_amdgcn_fdot2(av,bv,c,false);
#else
  h2v av,bv; __builtin_memcpy(&av,&a,4); __builtin_memcpy(&bv,&b,4);
  return c + (float)av[0]*(float)bv[0] + (float)av[1]*(float)bv[1];
#endif
}
__device__ __forceinline__ float sigmoidf(float x){ return 1.f/(1.f+__expf(-x)); }
__device__ __forceinline__ float tanh_fast(float x){ float e=__expf(2.f*x); return 1.f - 2.f/(e+1.f); }
__device__ __forceinline__ float wave_sum(float v){
  #pragma unroll
  for(int m=32;m>=1;m>>=1) v += __shfl_xor(v,m,64);
  return v;
}
__device__ __forceinline__ float wave_max(float v){
  #pragma unroll
  for(int m=32;m>=1;m>>=1) v = fmaxf(v,__shfl_xor(v,m,64));
  return v;
}

// ---------- dtype sniffer: fp32 data has random low-mantissa u16 halves ----------
__global__ void k_flag(const void* emb_raw, int* flag){
  const unsigned short* u=(const unsigned short*)emb_raw;
  int t=threadIdx.x, found=0;
  for(int i=t;i<2048;i+=256){ float v=bf16_to_f32(u[i]); if(fabsf(v)>8.f) found=1; }
  __shared__ int s;
  if(t==0) s=0;
  __syncthreads();
  if(found) atomicOr(&s,1);
  __syncthreads();
  if(t==0) *flag = s;   // 1 = inputs are fp32, 0 = inputs are bf16
}

struct ConvArgs { const void* src[25]; int len[25]; int off[25]; };

__global__ void k_convert(ConvArgs a, const int* __restrict__ flag, float* __restrict__ dst){
  int isf32=*flag;
  int idx=blockIdx.x*256+threadIdx.x;
  #pragma unroll 1
  for(int i=0;i<25;i++){
    if(idx < a.len[i]){
      float v = isf32 ? ((const float*)a.src[i])[idx]
                      : bf16_to_f32(((const unsigned short*)a.src[i])[idx]);
      dst[a.off[i]+idx]=v;
      return;
    }
    idx -= a.len[i];
  }
}

// ---------- prep: f16-pair transposed pooling weights + transposed mWih ----------
__global__ void k_prep(const float* __restrict__ cw, uint32_t* __restrict__ wpt2w,
                       uint32_t* __restrict__ wpt2p, float* __restrict__ mWihT){
  int idx=blockIdx.x*256+threadIdx.x;
  if(idx<16384){
    int kp=idx>>7, c=idx&127; const float* W=cw+C_WWP;
    wpt2w[idx]=pack_h2(W[c*256+2*kp], W[c*256+2*kp+1]);
  } else if(idx<32768){
    int i=idx-16384; int kp=i>>7, c=i&127; const float* W=cw+C_PWP;
    wpt2p[i]=pack_h2(W[c*256+2*kp], W[c*256+2*kp+1]);
  } else {
    int iN=idx-32768; int k=iN/768, g=iN-k*768;
    mWihT[iN] = (g<G3) ? cw[C_MWIH_F + g*256 + k] : cw[C_MWIH_B + (g-G3)*256 + k];
  }
}

// ---------- char BiGRU: thread g owns gate-row g (weights f16-packed in VGPRs) ----------
__global__ __launch_bounds__(384,3) void k_chargru(const int* __restrict__ chars,
    const int* __restrict__ lensp, const float* __restrict__ cw,
    unsigned short* __restrict__ chout){
  int dir=blockIdx.y, tid=threadIdx.x;
  int seq0=blockIdx.x*SPB;
  const float* emb=cw+C_EMB;
  const float* Wih=cw+(dir?C_CWIH_B:C_CWIH_F);
  const float* Whh=cw+(dir?C_CWHH_B:C_CWHH_F);
  const float* bih=cw+(dir?C_CBIH_B:C_CBIH_F);
  const float* bhh=cw+(dir?C_CBHH_B:C_CBHH_F);

  uint32_t wih[32], whh[64];
  {
    const float4* r4=(const float4*)(Wih + tid*EDIM);
    #pragma unroll
    for(int i=0;i<16;i++){ float4 v=r4[i]; wih[2*i]=pack_h2(v.x,v.y); wih[2*i+1]=pack_h2(v.z,v.w); }
    const float4* h4=(const float4*)(Whh + tid*HDIM);
    #pragma unroll
    for(int i=0;i<32;i++){ float4 v=h4[i]; whh[2*i]=pack_h2(v.x,v.y); whh[2*i+1]=pack_h2(v.z,v.w); }
  }
  float bih_g=bih[tid], bhh_g=bhh[tid];

  __shared__ __align__(16) unsigned short xh[SPB][EDIM];
  __shared__ __align__(16) unsigned short hh[SPB][HDIM];
  __shared__ float rr[SPB][HDIM], zz[SPB][HDIM], xns[SPB][HDIM], hns[SPB][HDIM];
  __shared__ int cid[SPB][CLEN];
  __shared__ int lenS[SPB];

  { int s=tid/CLEN, t=tid-s*CLEN; cid[s][t]=chars[(seq0+s)*CLEN+t]; }
  if(tid<SPB) lenS[tid]=lensp[seq0+tid];
  for(int i=tid;i<SPB*HDIM/2;i+=384) ((uint32_t*)hh)[i]=0u;
  float hreg[SPB];
  #pragma unroll
  for(int s=0;s<SPB;s++) hreg[s]=0.f;
  __syncthreads();

  int j=tid&127, gt=tid>>7;
  for(int step=0;step<CLEN;step++){
    int t = dir ? (CLEN-1-step) : step;
    if(tid<SPB*32){
      int s=tid>>5, e2=tid&31;
      const float* er=emb + cid[s][t]*EDIM + 2*e2;
      ((uint32_t*)xh)[s*32+e2]=pack_h2(er[0],er[1]);
    }
    __syncthreads();
    #pragma unroll
    for(int s=0;s<SPB;s++){
      float xa=bih_g, ha=bhh_g;
      const uint4* xp=(const uint4*)&xh[s][0];
      const uint4* hp=(const uint4*)&hh[s][0];
      #pragma unroll
      for(int q=0;q<8;q++){ uint4 v=xp[q];
        xa=dot2(wih[4*q+0],v.x,xa); xa=dot2(wih[4*q+1],v.y,xa);
        xa=dot2(wih[4*q+2],v.z,xa); xa=dot2(wih[4*q+3],v.w,xa); }
      #pragma unroll
      for(int q=0;q<16;q++){ uint4 v=hp[q];
        ha=dot2(whh[4*q+0],v.x,ha); ha=dot2(whh[4*q+1],v.y,ha);
        ha=dot2(whh[4*q+2],v.z,ha); ha=dot2(whh[4*q+3],v.w,ha); }
      if(gt==0)      rr[s][j]=sigmoidf(xa+ha);
      else if(gt==1) zz[s][j]=sigmoidf(xa+ha);
      else { xns[s][j]=xa; hns[s][j]=ha; }
    }
    __syncthreads();
    if(tid<HDIM){
      #pragma unroll
      for(int s=0;s<SPB;s++){
        float r=rr[s][tid], z=zz[s][tid];
        float nn=tanh_fast(xns[s][tid] + r*hns[s][tid]);
        float hnew=(1.f-z)*nn + z*hreg[s];
        bool valid = t < lenS[s];
        float hv = valid ? hnew : hreg[s];
        hreg[s]=hv;
        hh[s][tid]=f32_to_h16u(hv);
        chout[((size_t)(seq0+s)*CLEN+t)*256 + dir*HDIM + tid] =
            valid ? f32_to_h16u(hnew) : (unsigned short)0;
      }
    }
    __syncthreads();
  }
}

// ---------- attention pooling (T=48 words / T=64 messages; MSG fuses final linear) ----------
template<int T,int MSG>
__global__ __launch_bounds__(256) void k_pool(const unsigned short* __restrict__ outp,
    const uint32_t* __restrict__ WpT2, const float* __restrict__ bp,
    const float* __restrict__ ctxv, float* __restrict__ dst,
    const float* __restrict__ Wout, const float* __restrict__ bout,
    void* dout, const int* __restrict__ flag){
  constexpr int NT=T/2;
  int n=blockIdx.x, tid=threadIdx.x;
  __shared__ uint32_t so[T][128];
  __shared__ float red[T][2];
  __shared__ float att[T];
  __shared__ float msgv[256];
  {
    const uint4* src=(const uint4*)(outp + (size_t)n*T*256);
    uint4* d4=(uint4*)&so[0][0];
    #pragma unroll 1
    for(int i=tid;i<T*32;i+=256) d4[i]=src[i];
  }
  __syncthreads();
  int c=tid&127, tt=tid>>7;
  float acc[NT];
  float bpc=bp[c];
  #pragma unroll
  for(int i=0;i<NT;i++) acc[i]=bpc;
  for(int kp=0;kp<128;kp++){
    uint32_t w2=WpT2[kp*128+c];
    #pragma unroll
    for(int i=0;i<NT;i++) acc[i]=dot2(w2, so[2*i+tt][kp], acc[i]);
  }
  float cv=ctxv[c];
  #pragma unroll
  for(int i=0;i<NT;i++){
    float lg=tanh_fast(acc[i])*cv;
    lg=wave_sum(lg);
    if((tid&63)==0) red[2*i+tt][(tid>>6)&1]=lg;
  }
  __syncthreads();
  if(tid<64){
    float v = (tid<T) ? (red[tid][0]+red[tid][1]) : -1e30f;
    float m = wave_max(v);
    float e = (tid<T) ? __expf(v-m) : 0.f;
    float s = wave_sum(e);
    if(tid<T) att[tid]=e/s;
  }
  __syncthreads();
  if(tid<128){
    float a0=0.f, a1=0.f;
    #pragma unroll 1
    for(int t=0;t<T;t++){
      uint32_t u=so[t][tid];
      float at=att[t];
      a0=fmaf(at,h16lo(u),a0);
      a1=fmaf(at,h16hi(u),a1);
    }
    if constexpr(!MSG){
      float2* d2=(float2*)dst;
      d2[(size_t)n*128+tid]=make_float2(a0,a1);
    } else {
      msgv[2*tid]=a0; msgv[2*tid+1]=a1;
      if(*flag){ float* mo=(float*)dout + 1024 + n*256; mo[2*tid]=a0; mo[2*tid+1]=a1; }
      else { unsigned short* mo=(unsigned short*)dout + 1024 + n*256;
             mo[2*tid]=f32_to_bf16(a0); mo[2*tid+1]=f32_to_bf16(a1); }
    }
  }
  if constexpr(MSG){
    __syncthreads();
    if(tid<OUTD){
      float a=bout[tid];
      #pragma unroll 1
      for(int k=0;k<256;k++) a=fmaf(msgv[k], Wout[tid*256+k], a);
      if(*flag) ((float*)dout)[n*OUTD+tid]=a;
      else ((unsigned short*)dout)[n*OUTD+tid]=f32_to_bf16(a);
    }
  }
}

// ---------- message input-gate GEMM: xgm[dir][n][384] = words@WihT + bih ----------
__global__ __launch_bounds__(256) void k_msgxg(const float* __restrict__ words,
    const float* __restrict__ mWihT, const float* __restrict__ cw, float* __restrict__ xgm){
  int n0=blockIdx.x*16, tid=threadIdx.x;
  __shared__ float wl[16][256];
  #pragma unroll 1
  for(int i=tid;i<16*256;i+=256) ((float*)wl)[i]=words[(size_t)n0*256+i];
  __syncthreads();
  int g0=tid, g1=tid+256, g2=tid+512;
  float b0 = (g0<G3)? cw[C_MBIH_F+g0] : cw[C_MBIH_B+g0-G3];
  float b1 = (g1<G3)? cw[C_MBIH_F+g1] : cw[C_MBIH_B+g1-G3];
  float b2 = (g2<G3)? cw[C_MBIH_F+g2] : cw[C_MBIH_B+g2-G3];
  float a0[16],a1[16],a2[16];
  #pragma unroll
  for(int w=0;w<16;w++){ a0[w]=b0; a1[w]=b1; a2[w]=b2; }
  for(int k=0;k<256;k++){
    float w0=mWihT[k*768+g0], w1=mWihT[k*768+g1], w2v=mWihT[k*768+g2];
    #pragma unroll
    for(int w=0;w<16;w++){
      float x=wl[w][k];
      a0[w]=fmaf(x,w0,a0[w]); a1[w]=fmaf(x,w1,a1[w]); a2[w]=fmaf(x,w2v,a2[w]);
    }
  }
  for(int w=0;w<16;w++){
    int n=n0+w;
    { int g=g0; float v=a0[w]; if(g<G3) xgm[(size_t)n*G3+g]=v; else xgm[(size_t)NW*G3+(size_t)n*G3+g-G3]=v; }
    { int g=g1; float v=a1[w]; if(g<G3) xgm[(size_t)n*G3+g]=v; else xgm[(size_t)NW*G3+(size_t)n*G3+g-G3]=v; }
    { int g=g2; float v=a2[w]; if(g<G3) xgm[(size_t)n*G3+g]=v; else xgm[(size_t)NW*G3+(size_t)n*G3+g-G3]=v; }
  }
}

// ---------- message BiGRU (lens = full W, no masking) ----------
__global__ __launch_bounds__(384) void k_msggru(const float* __restrict__ cw,
    const float* __restrict__ xgm, unsigned short* __restrict__ msg_out){
  int dir=blockIdx.y, b=blockIdx.x, tid=threadIdx.x;
  const float* Whh=cw+(dir?C_MWHH_B:C_MWHH_F);
  const float* bhh=cw+(dir?C_MBHH_B:C_MBHH_F);
  const float* xg = xgm + (size_t)dir*NW*G3;
  uint32_t whh[64];
  {
    const float4* h4=(const float4*)(Whh + tid*HDIM);
    #pragma unroll
    for(int i=0;i<32;i++){ float4 v=h4[i]; whh[2*i]=pack_h2(v.x,v.y); whh[2*i+1]=pack_h2(v.z,v.w); }
  }
  float bhh_g=bhh[tid];
  __shared__ __align__(16) unsigned short hh[HDIM];
  __shared__ float rr[HDIM], zz[HDIM], xns[HDIM], hns[HDIM];
  if(tid<64) ((uint32_t*)hh)[tid]=0u;
  float hreg=0.f;
  __syncthreads();
  int j=tid&127, gt=tid>>7;
  for(int step=0;step<WRD;step++){
    int w = dir ? (WRD-1-step) : step;
    float xacc = xg[(size_t)(b*WRD+w)*G3 + tid];
    float ha=bhh_g;
    const uint4* hp=(const uint4*)hh;
    #pragma unroll
    for(int q=0;q<16;q++){ uint4 v=hp[q];
      ha=dot2(whh[4*q+0],v.x,ha); ha=dot2(whh[4*q+1],v.y,ha);
      ha=dot2(whh[4*q+2],v.z,ha); ha=dot2(whh[4*q+3],v.w,ha); }
    if(gt==0)      rr[j]=sigmoidf(xacc+ha);
    else if(gt==1) zz[j]=sigmoidf(xacc+ha);
    else { xns[j]=xacc; hns[j]=ha; }
    __syncthreads();
    if(tid<HDIM){
      float r=rr[tid], z=zz[tid];
      float nn=tanh_fast(xns[tid]+r*hns[tid]);
      float hnew=(1.f-z)*nn + z*hreg;
      hreg=hnew;
      hh[tid]=f32_to_h16u(hnew);
      msg_out[(size_t)(b*WRD+w)*256 + dir*HDIM + tid]=f32_to_h16u(hnew);
    }
    __syncthreads();
  }
}

extern "C" void kernel_launch(void* const* d_in, const int* in_sizes, int n_in,
                              void* d_out, int out_size, void* d_ws, size_t ws_size,
                              hipStream_t stream){
  (void)in_sizes; (void)n_in; (void)out_size; (void)ws_size;
  char* ws=(char*)d_ws;
  int* flag=(int*)(ws+OFF_FLAG);
  float* canon=(float*)(ws+OFF_CANON);
  uint32_t* wpt2w=(uint32_t*)(ws+OFF_WPT2_W);
  uint32_t* wpt2p=(uint32_t*)(ws+OFF_WPT2_P);
  float* mWihT=(float*)(ws+OFF_MWIHT);
  float* xgm=(float*)(ws+OFF_XGM);
  float* words=(float*)(ws+OFF_WORDS);
  unsigned short* msgout=(unsigned short*)(ws+OFF_MSGOUT);
  unsigned short* chout=(unsigned short*)(ws+OFF_CHOUT);
  const int* chars=(const int*)d_in[0];
  const int* lensp=(const int*)d_in[1];

  hipLaunchKernelGGL(k_flag, dim3(1), dim3(256), 0, stream, d_in[2], flag);

  ConvArgs ca;
  static const int clen_[25]={16384,24576,49152,384,384,24576,49152,384,384,
                              98304,49152,768,768,98304,49152,768,768,
                              32768,128,128,32768,128,128,2048,8};
  int off=0;
  for(int i=0;i<25;i++){ ca.src[i]=d_in[i+2]; ca.len[i]=clen_[i]; ca.off[i]=off; off+=clen_[i]; }
  hipLaunchKernelGGL(k_convert, dim3((C_TOTAL+255)/256), dim3(256), 0, stream, ca, flag, canon);
  hipLaunchKernelGGL(k_prep, dim3(896), dim3(256), 0, stream, canon, wpt2w, wpt2p, mWihT);
  hipLaunchKernelGGL(k_chargru, dim3(NW/SPB,2), dim3(384), 0, stream, chars, lensp, canon, chout);
  hipLaunchKernelGGL((k_pool<48,0>), dim3(NW), dim3(256), 0, stream, chout, wpt2w,
                     canon+C_WBP, canon+C_WCTX, words,
                     (const float*)nullptr, (const float*)nullptr, (void*)nullptr, (const int*)nullptr);
  hipLaunchKernelGGL(k_msgxg, dim3(NW/16), dim3(256), 0, stream, words, mWihT, canon, xgm);
  hipLaunchKernelGGL(k_msggru, dim3(BATCH,2), dim3(384), 0, stream, canon, xgm, msgout);
  hipLaunchKernelGGL((k_pool<64,1>), dim3(BATCH), dim3(256), 0, stream, msgout, wpt2p,
                     canon+C_PBP, canon+C_PCTX, (float*)nullptr,
                     canon+C_WOUT, canon+C_BOUT, d_out, flag);
}

// Round 2
// 1099.061 us; speedup vs baseline: 2.5901x; 2.5901x over previous
//
#include <hip/hip_runtime.h>
#include <stdint.h>
#include <stddef.h>

#define NCH   256
#define EDIM  64
#define HDIM  128
#define G3    384
#define BATCH 128
#define WRD   64
#define CLEN  48
#define NW    8192
#define OUTD  8

// ---- canonical fp32 weight offsets (element units) ----
#define C_EMB     0
#define C_CWIH_F  16384
#define C_CWHH_F  40960
#define C_CBIH_F  90112
#define C_CBHH_F  90496
#define C_CWIH_B  90880
#define C_CWHH_B  115456
#define C_CBIH_B  164608
#define C_CBHH_B  164992
#define C_MWIH_F  165376
#define C_MWHH_F  263680
#define C_MBIH_F  312832
#define C_MBHH_F  313600
#define C_MWIH_B  314368
#define C_MWHH_B  412672
#define C_MBIH_B  461824
#define C_MBHH_B  462592
#define C_WWP     463360
#define C_WBP     496128
#define C_WCTX    496256
#define C_PWP     496384
#define C_PBP     529152
#define C_PCTX    529280
#define C_WOUT    529408
#define C_BOUT    531456
#define C_TOTAL   531464

// ---- ws byte offsets ----
#define OFF_FLAG    0u
#define OFF_CANON   1024u
#define OFF_WPT2_W  (4u*1024u*1024u)
#define OFF_WPT2_P  (4u*1024u*1024u + 65536u)
#define OFF_MWIHT   (4u*1024u*1024u + 131072u)
#define OFF_XGM     (8u*1024u*1024u)
#define OFF_WORDS   35651584u
#define OFF_MSGOUT  47185920u
#define OFF_CHOUT   54525952u

typedef _Float16 h2v __attribute__((ext_vector_type(2)));
typedef _Float16 f16x8 __attribute__((ext_vector_type(8)));
typedef float f32x4 __attribute__((ext_vector_type(4)));

__device__ __forceinline__ float bf16_to_f32(unsigned short u){
  union{unsigned int i;float f;}v; v.i=((unsigned int)u)<<16; return v.f;
}
__device__ __forceinline__ unsigned short f32_to_bf16(float f){
  union{float f;unsigned int i;}v; v.f=f;
  unsigned int u=v.i; unsigned int r=(u + 0x7fffu + ((u>>16)&1u))>>16;
  return (unsigned short)r;
}
__device__ __forceinline__ uint32_t pack_h2(float x,float y){
  h2v h; h[0]=(_Float16)x; h[1]=(_Float16)y; uint32_t u; __builtin_memcpy(&u,&h,4); return u;
}
__device__ __forceinline__ unsigned short f32_to_h16u(float f){
  _Float16 h=(_Float16)f; unsigned short u; __builtin_memcpy(&u,&h,2); return u;
}
__device__ __forceinline__ float h16lo(uint32_t u){
  unsigned short s=(unsigned short)(u&0xffffu); _Float16 h; __builtin_memcpy(&h,&s,2); return (float)h;
}
__device__ __forceinline__ float h16hi(uint32_t u){
  unsigned short s=(unsigned short)(u>>16); _Float16 h; __builtin_memcpy(&h,&s,2); return (float)h;
}
__device__ __forceinline__ float dot2(uint32_t a, uint32_t b, float c){
#if __has_builtin(__builtin_amdgcn_fdot2)
  h2v av,bv; __builtin_memcpy(&av,&a,4); __builtin_memcpy(&bv,&b,4);
  return __builtin_amdgcn_fdot2(av,bv,c,false);
#else
  h2v av,bv; __builtin_memcpy(&av,&a,4); __builtin_memcpy(&bv,&b,4);
  return c + (float)av[0]*(float)bv[0] + (float)av[1]*(float)bv[1];
#endif
}
__device__ __forceinline__ float sigmoidf(float x){ return 1.f/(1.f+__expf(-x)); }
__device__ __forceinline__ float tanh_fast(float x){ float e=__expf(2.f*x); return 1.f - 2.f/(e+1.f); }
__device__ __forceinline__ float wave_sum(float v){
  #pragma unroll
  for(int m=32;m>=1;m>>=1) v += __shfl_xor(v,m,64);
  return v;
}
__device__ __forceinline__ float wave_max(float v){
  #pragma unroll
  for(int m=32;m>=1;m>>=1) v = fmaxf(v,__shfl_xor(v,m,64));
  return v;
}
__device__ __forceinline__ f32x4 mfma16(f16x8 a, f16x8 b, f32x4 c){
  return __builtin_amdgcn_mfma_f32_16x16x32_f16(a, b, c, 0, 0, 0);
}

// ---------- dtype sniffer ----------
__global__ void k_flag(const void* emb_raw, int* flag){
  const unsigned short* u=(const unsigned short*)emb_raw;
  int t=threadIdx.x, found=0;
  for(int i=t;i<2048;i+=256){ float v=bf16_to_f32(u[i]); if(fabsf(v)>8.f) found=1; }
  __shared__ int s;
  if(t==0) s=0;
  __syncthreads();
  if(found) atomicOr(&s,1);
  __syncthreads();
  if(t==0) *flag = s;
}

struct ConvArgs { const void* src[25]; int len[25]; int off[25]; };

__global__ void k_convert(ConvArgs a, const int* __restrict__ flag, float* __restrict__ dst){
  int isf32=*flag;
  int idx=blockIdx.x*256+threadIdx.x;
  #pragma unroll 1
  for(int i=0;i<25;i++){
    if(idx < a.len[i]){
      float v = isf32 ? ((const float*)a.src[i])[idx]
                      : bf16_to_f32(((const unsigned short*)a.src[i])[idx]);
      dst[a.off[i]+idx]=v;
      return;
    }
    idx -= a.len[i];
  }
}

// ---------- prep ----------
__global__ void k_prep(const float* __restrict__ cw, uint32_t* __restrict__ wpt2w,
                       uint32_t* __restrict__ wpt2p, float* __restrict__ mWihT){
  int idx=blockIdx.x*256+threadIdx.x;
  if(idx<16384){
    int kp=idx>>7, c=idx&127; const float* W=cw+C_WWP;
    wpt2w[idx]=pack_h2(W[c*256+2*kp], W[c*256+2*kp+1]);
  } else if(idx<32768){
    int i=idx-16384; int kp=i>>7, c=i&127; const float* W=cw+C_PWP;
    wpt2p[i]=pack_h2(W[c*256+2*kp], W[c*256+2*kp+1]);
  } else {
    int iN=idx-32768; int k=iN/768, g=iN-k*768;
    mWihT[iN] = (g<G3) ? cw[C_MWIH_F + g*256 + k] : cw[C_MWIH_B + (g-G3)*256 + k];
  }
}

// ---------- char BiGRU via MFMA: 16 seqs/block, 8 waves, gates = [h|x]@W^T ----------
// Wave w owns N-tiles {w, w+8, w+16}: cols {w*16.., 128+w*16.., 256+w*16..}.
// r/z tiles: x-part accumulated into same acc (pre-biased). n tile: hn/xn separate.
__global__ __launch_bounds__(512,4) void k_chargru(const int* __restrict__ chars,
    const int* __restrict__ lensp, const float* __restrict__ cw,
    unsigned short* __restrict__ chout){
  int tid=threadIdx.x;
  int w=tid>>6, L=tid&63, nl=L&15, q=L>>4;
  int dir=blockIdx.y;
  int seq0=blockIdx.x*16;
  const float* emb=cw+C_EMB;
  const float* Wih=cw+(dir?C_CWIH_B:C_CWIH_F);
  const float* Whh=cw+(dir?C_CWHH_B:C_CWHH_F);
  const float* bih=cw+(dir?C_CBIH_B:C_CBIH_F);
  const float* bhh=cw+(dir?C_CBHH_B:C_CBHH_F);

  // --- persistent B fragments (step-invariant weights), f16 ---
  f16x8 bh[3][4], bx[3][2];
  float bias_rz0, bias_rz1, bias_hn, bias_xn;
  #pragma unroll
  for(int i=0;i<3;i++){
    int tile=w+8*i, n=tile*16+nl;
    const float* wr=Whh + n*HDIM;
    #pragma unroll
    for(int c=0;c<4;c++){
      const float4* p=(const float4*)(wr + c*32 + q*8);
      float4 v0=p[0], v1=p[1];
      f16x8 f;
      f[0]=(_Float16)v0.x; f[1]=(_Float16)v0.y; f[2]=(_Float16)v0.z; f[3]=(_Float16)v0.w;
      f[4]=(_Float16)v1.x; f[5]=(_Float16)v1.y; f[6]=(_Float16)v1.z; f[7]=(_Float16)v1.w;
      bh[i][c]=f;
    }
    const float* xr=Wih + n*EDIM;
    #pragma unroll
    for(int c=0;c<2;c++){
      const float4* p=(const float4*)(xr + c*32 + q*8);
      float4 v0=p[0], v1=p[1];
      f16x8 f;
      f[0]=(_Float16)v0.x; f[1]=(_Float16)v0.y; f[2]=(_Float16)v0.z; f[3]=(_Float16)v0.w;
      f[4]=(_Float16)v1.x; f[5]=(_Float16)v1.y; f[6]=(_Float16)v1.z; f[7]=(_Float16)v1.w;
      bx[i][c]=f;
    }
    float bi=bih[n], bo=bhh[n];
    if(i==0) bias_rz0=bi+bo;
    else if(i==1) bias_rz1=bi+bo;
    else { bias_hn=bo; bias_xn=bi; }
  }

  __shared__ int cid[16][CLEN];
  __shared__ int lenS[16];
  __shared__ __align__(16) _Float16 hbuf[16][136];     // stride 68 dw == 4 mod 32
  __shared__ __align__(16) _Float16 xbuf[2][16][72];   // stride 36 dw == 4 mod 32
  __shared__ float Grz[16][260];                       // 260 == 4 mod 32
  __shared__ float Ghn[16][132];
  __shared__ float Gxn[16][132];

  for(int i=tid;i<16*CLEN;i+=512){ int s=i/CLEN, c=i-CLEN*s; cid[s][c]=chars[(seq0+s)*CLEN+c]; }
  if(tid<16) lenS[tid]=lensp[seq0+tid];
  for(int i=tid;i<16*136/2;i+=512) ((uint32_t*)hbuf)[i]=0u;
  __syncthreads();
  // load x(t0)
  {
    int sp=tid>>5, e2=tid&31;
    int t0 = dir ? CLEN-1 : 0;
    const float* er = emb + cid[sp][t0]*EDIM + 2*e2;
    ((uint32_t*)&xbuf[0][sp][0])[e2] = pack_h2(er[0], er[1]);
  }
  __syncthreads();

  float hreg[4]={0.f,0.f,0.f,0.f};
  int colA=w*16+nl, colB=(w+8)*16+nl;
  int jj=tid&127, s0=tid>>7;
  int sp=tid>>5, e2=tid&31;

  for(int step=0; step<CLEN; ++step){
    int t = dir ? CLEN-1-step : step;
    // prefetch next x into regs (L2-resident emb)
    float pf0=0.f, pf1=0.f;
    bool havepf = (step+1 < CLEN);
    if(havepf){
      int tn = dir ? CLEN-2-step : step+1;
      const float* er = emb + cid[sp][tn]*EDIM + 2*e2;
      pf0=er[0]; pf1=er[1];
    }
    // ---- MFMA phase ----
    f32x4 acc0={bias_rz0,bias_rz0,bias_rz0,bias_rz0};
    f32x4 acc1={bias_rz1,bias_rz1,bias_rz1,bias_rz1};
    f32x4 a2h ={bias_hn,bias_hn,bias_hn,bias_hn};
    f32x4 a2x ={bias_xn,bias_xn,bias_xn,bias_xn};
    const _Float16* hrow=&hbuf[nl][0];
    #pragma unroll
    for(int c=0;c<4;c++){
      f16x8 af = *(const f16x8*)(hrow + c*32 + q*8);
      acc0=mfma16(af, bh[0][c], acc0);
      acc1=mfma16(af, bh[1][c], acc1);
      a2h =mfma16(af, bh[2][c], a2h);
    }
    const _Float16* xrow=&xbuf[step&1][nl][0];
    #pragma unroll
    for(int c=0;c<2;c++){
      f16x8 af = *(const f16x8*)(xrow + c*32 + q*8);
      acc0=mfma16(af, bx[0][c], acc0);
      acc1=mfma16(af, bx[1][c], acc1);
      a2x =mfma16(af, bx[2][c], a2x);
    }
    // D layout: row(m=seq)=q*4+reg, col(n=gate)=nl
    #pragma unroll
    for(int r=0;r<4;r++){
      int m=q*4+r;
      Grz[m][colA]=acc0[r];
      Grz[m][colB]=acc1[r];
      Ghn[m][colA]=a2h[r];
      Gxn[m][colA]=a2x[r];
    }
    __syncthreads();
    // ---- elementwise GRU update ----
    #pragma unroll
    for(int u=0;u<4;u++){
      int s=s0+4*u;
      float r=sigmoidf(Grz[s][jj]);
      float z=sigmoidf(Grz[s][jj+128]);
      float nn=tanh_fast(Gxn[s][jj] + r*Ghn[s][jj]);
      float hnew=(1.f-z)*nn + z*hreg[u];
      bool valid = t < lenS[s];
      float hv = valid ? hnew : hreg[u];
      hreg[u]=hv;
      hbuf[s][jj]=(_Float16)hv;
      chout[((size_t)(seq0+s)*CLEN+t)*256 + dir*HDIM + jj] = valid ? f32_to_h16u(hnew) : (unsigned short)0;
    }
    if(havepf) ((uint32_t*)&xbuf[(step+1)&1][sp][0])[e2] = pack_h2(pf0,pf1);
    __syncthreads();
  }
}

// ---------- attention pooling ----------
template<int T,int MSG>
__global__ __launch_bounds__(256) void k_pool(const unsigned short* __restrict__ outp,
    const uint32_t* __restrict__ WpT2, const float* __restrict__ bp,
    const float* __restrict__ ctxv, float* __restrict__ dst,
    const float* __restrict__ Wout, const float* __restrict__ bout,
    void* dout, const int* __restrict__ flag){
  constexpr int NT=T/2;
  int n=blockIdx.x, tid=threadIdx.x;
  __shared__ uint32_t so[T][128];
  __shared__ float red[T][2];
  __shared__ float att[T];
  __shared__ float msgv[256];
  {
    const uint4* src=(const uint4*)(outp + (size_t)n*T*256);
    uint4* d4=(uint4*)&so[0][0];
    #pragma unroll 1
    for(int i=tid;i<T*32;i+=256) d4[i]=src[i];
  }
  __syncthreads();
  int c=tid&127, tt=tid>>7;
  float acc[NT];
  float bpc=bp[c];
  #pragma unroll
  for(int i=0;i<NT;i++) acc[i]=bpc;
  for(int kp=0;kp<128;kp++){
    uint32_t w2=WpT2[kp*128+c];
    #pragma unroll
    for(int i=0;i<NT;i++) acc[i]=dot2(w2, so[2*i+tt][kp], acc[i]);
  }
  float cv=ctxv[c];
  #pragma unroll
  for(int i=0;i<NT;i++){
    float lg=tanh_fast(acc[i])*cv;
    lg=wave_sum(lg);
    if((tid&63)==0) red[2*i+tt][(tid>>6)&1]=lg;
  }
  __syncthreads();
  if(tid<64){
    float v = (tid<T) ? (red[tid][0]+red[tid][1]) : -1e30f;
    float m = wave_max(v);
    float e = (tid<T) ? __expf(v-m) : 0.f;
    float s = wave_sum(e);
    if(tid<T) att[tid]=e/s;
  }
  __syncthreads();
  if(tid<128){
    float a0=0.f, a1=0.f;
    #pragma unroll 1
    for(int t=0;t<T;t++){
      uint32_t u=so[t][tid];
      float at=att[t];
      a0=fmaf(at,h16lo(u),a0);
      a1=fmaf(at,h16hi(u),a1);
    }
    if constexpr(!MSG){
      float2* d2=(float2*)dst;
      d2[(size_t)n*128+tid]=make_float2(a0,a1);
    } else {
      msgv[2*tid]=a0; msgv[2*tid+1]=a1;
      if(*flag){ float* mo=(float*)dout + 1024 + n*256; mo[2*tid]=a0; mo[2*tid+1]=a1; }
      else { unsigned short* mo=(unsigned short*)dout + 1024 + n*256;
             mo[2*tid]=f32_to_bf16(a0); mo[2*tid+1]=f32_to_bf16(a1); }
    }
  }
  if constexpr(MSG){
    __syncthreads();
    if(tid<OUTD){
      float a=bout[tid];
      #pragma unroll 1
      for(int k=0;k<256;k++) a=fmaf(msgv[k], Wout[tid*256+k], a);
      if(*flag) ((float*)dout)[n*OUTD+tid]=a;
      else ((unsigned short*)dout)[n*OUTD+tid]=f32_to_bf16(a);
    }
  }
}

// ---------- message input-gate GEMM ----------
__global__ __launch_bounds__(256) void k_msgxg(const float* __restrict__ words,
    const float* __restrict__ mWihT, const float* __restrict__ cw, float* __restrict__ xgm){
  int n0=blockIdx.x*16, tid=threadIdx.x;
  __shared__ float wl[16][256];
  #pragma unroll 1
  for(int i=tid;i<16*256;i+=256) ((float*)wl)[i]=words[(size_t)n0*256+i];
  __syncthreads();
  int g0=tid, g1=tid+256, g2=tid+512;
  float b0 = (g0<G3)? cw[C_MBIH_F+g0] : cw[C_MBIH_B+g0-G3];
  float b1 = (g1<G3)? cw[C_MBIH_F+g1] : cw[C_MBIH_B+g1-G3];
  float b2 = (g2<G3)? cw[C_MBIH_F+g2] : cw[C_MBIH_B+g2-G3];
  float a0[16],a1[16],a2[16];
  #pragma unroll
  for(int w=0;w<16;w++){ a0[w]=b0; a1[w]=b1; a2[w]=b2; }
  for(int k=0;k<256;k++){
    float w0=mWihT[k*768+g0], w1=mWihT[k*768+g1], w2v=mWihT[k*768+g2];
    #pragma unroll
    for(int w=0;w<16;w++){
      float x=wl[w][k];
      a0[w]=fmaf(x,w0,a0[w]); a1[w]=fmaf(x,w1,a1[w]); a2[w]=fmaf(x,w2v,a2[w]);
    }
  }
  for(int w=0;w<16;w++){
    int n=n0+w;
    { int g=g0; float v=a0[w]; if(g<G3) xgm[(size_t)n*G3+g]=v; else xgm[(size_t)NW*G3+(size_t)n*G3+g-G3]=v; }
    { int g=g1; float v=a1[w]; if(g<G3) xgm[(size_t)n*G3+g]=v; else xgm[(size_t)NW*G3+(size_t)n*G3+g-G3]=v; }
    { int g=g2; float v=a2[w]; if(g<G3) xgm[(size_t)n*G3+g]=v; else xgm[(size_t)NW*G3+(size_t)n*G3+g-G3]=v; }
  }
}

// ---------- message BiGRU ----------
__global__ __launch_bounds__(384) void k_msggru(const float* __restrict__ cw,
    const float* __restrict__ xgm, unsigned short* __restrict__ msg_out){
  int dir=blockIdx.y, b=blockIdx.x, tid=threadIdx.x;
  const float* Whh=cw+(dir?C_MWHH_B:C_MWHH_F);
  const float* bhh=cw+(dir?C_MBHH_B:C_MBHH_F);
  const float* xg = xgm + (size_t)dir*NW*G3;
  uint32_t whh[64];
  {
    const float4* h4=(const float4*)(Whh + tid*HDIM);
    #pragma unroll
    for(int i=0;i<32;i++){ float4 v=h4[i]; whh[2*i]=pack_h2(v.x,v.y); whh[2*i+1]=pack_h2(v.z,v.w); }
  }
  float bhh_g=bhh[tid];
  __shared__ __align__(16) unsigned short hh[HDIM];
  __shared__ float rr[HDIM], zz[HDIM], xns[HDIM], hns[HDIM];
  if(tid<64) ((uint32_t*)hh)[tid]=0u;
  float hreg=0.f;
  __syncthreads();
  int j=tid&127, gt=tid>>7;
  for(int step=0;step<WRD;step++){
    int w = dir ? (WRD-1-step) : step;
    float xacc = xg[(size_t)(b*WRD+w)*G3 + tid];
    float ha=bhh_g;
    const uint4* hp=(const uint4*)hh;
    #pragma unroll
    for(int q=0;q<16;q++){ uint4 v=hp[q];
      ha=dot2(whh[4*q+0],v.x,ha); ha=dot2(whh[4*q+1],v.y,ha);
      ha=dot2(whh[4*q+2],v.z,ha); ha=dot2(whh[4*q+3],v.w,ha); }
    if(gt==0)      rr[j]=sigmoidf(xacc+ha);
    else if(gt==1) zz[j]=sigmoidf(xacc+ha);
    else { xns[j]=xacc; hns[j]=ha; }
    __syncthreads();
    if(tid<HDIM){
      float r=rr[tid], z=zz[tid];
      float nn=tanh_fast(xns[tid]+r*hns[tid]);
      float hnew=(1.f-z)*nn + z*hreg;
      hreg=hnew;
      hh[tid]=f32_to_h16u(hnew);
      msg_out[(size_t)(b*WRD+w)*256 + dir*HDIM + tid]=f32_to_h16u(hnew);
    }
    __syncthreads();
  }
}

extern "C" void kernel_launch(void* const* d_in, const int* in_sizes, int n_in,
                              void* d_out, int out_size, void* d_ws, size_t ws_size,
                              hipStream_t stream){
  (void)in_sizes; (void)n_in; (void)out_size; (void)ws_size;
  char* ws=(char*)d_ws;
  int* flag=(int*)(ws+OFF_FLAG);
  float* canon=(float*)(ws+OFF_CANON);
  uint32_t* wpt2w=(uint32_t*)(ws+OFF_WPT2_W);
  uint32_t* wpt2p=(uint32_t*)(ws+OFF_WPT2_P);
  float* mWihT=(float*)(ws+OFF_MWIHT);
  float* xgm=(float*)(ws+OFF_XGM);
  float* words=(float*)(ws+OFF_WORDS);
  unsigned short* msgout=(unsigned short*)(ws+OFF_MSGOUT);
  unsigned short* chout=(unsigned short*)(ws+OFF_CHOUT);
  const int* chars=(const int*)d_in[0];
  const int* lensp=(const int*)d_in[1];

  hipLaunchKernelGGL(k_flag, dim3(1), dim3(256), 0, stream, d_in[2], flag);

  ConvArgs ca;
  static const int clen_[25]={16384,24576,49152,384,384,24576,49152,384,384,
                              98304,49152,768,768,98304,49152,768,768,
                              32768,128,128,32768,128,128,2048,8};
  int off=0;
  for(int i=0;i<25;i++){ ca.src[i]=d_in[i+2]; ca.len[i]=clen_[i]; ca.off[i]=off; off+=clen_[i]; }
  hipLaunchKernelGGL(k_convert, dim3((C_TOTAL+255)/256), dim3(256), 0, stream, ca, flag, canon);
  hipLaunchKernelGGL(k_prep, dim3(896), dim3(256), 0, stream, canon, wpt2w, wpt2p, mWihT);
  hipLaunchKernelGGL(k_chargru, dim3(NW/16,2), dim3(512), 0, stream, chars, lensp, canon, chout);
  hipLaunchKernelGGL((k_pool<48,0>), dim3(NW), dim3(256), 0, stream, chout, wpt2w,
                     canon+C_WBP, canon+C_WCTX, words,
                     (const float*)nullptr, (const float*)nullptr, (void*)nullptr, (const int*)nullptr);
  hipLaunchKernelGGL(k_msgxg, dim3(NW/16), dim3(256), 0, stream, words, mWihT, canon, xgm);
  hipLaunchKernelGGL(k_msggru, dim3(BATCH,2), dim3(384), 0, stream, canon, xgm, msgout);
  hipLaunchKernelGGL((k_pool<64,1>), dim3(BATCH), dim3(256), 0, stream, msgout, wpt2p,
                     canon+C_PBP, canon+C_PCTX, (float*)nullptr,
                     canon+C_WOUT, canon+C_BOUT, d_out, flag);
}

// Round 3
// 732.952 us; speedup vs baseline: 3.8838x; 1.4995x over previous
//
#include <hip/hip_runtime.h>
#include <stdint.h>
#include <stddef.h>

#define NCH   256
#define EDIM  64
#define HDIM  128
#define G3    384
#define BATCH 128
#define WRD   64
#define CLEN  48
#define NW    8192
#define OUTD  8

// ---- canonical fp32 weight offsets (element units) ----
#define C_EMB     0
#define C_CWIH_F  16384
#define C_CWHH_F  40960
#define C_CBIH_F  90112
#define C_CBHH_F  90496
#define C_CWIH_B  90880
#define C_CWHH_B  115456
#define C_CBIH_B  164608
#define C_CBHH_B  164992
#define C_MWIH_F  165376
#define C_MWHH_F  263680
#define C_MBIH_F  312832
#define C_MBHH_F  313600
#define C_MWIH_B  314368
#define C_MWHH_B  412672
#define C_MBIH_B  461824
#define C_MBHH_B  462592
#define C_WWP     463360
#define C_WBP     496128
#define C_WCTX    496256
#define C_PWP     496384
#define C_PBP     529152
#define C_PCTX    529280
#define C_WOUT    529408
#define C_BOUT    531456
#define C_TOTAL   531464

// ---- ws byte offsets ----
#define OFF_FLAG    0u
#define OFF_CANON   1024u
#define OFF_WPFRAG  (4u*1024u*1024u)              // 32768 f16 = 65536 B
#define OFF_WPT2_P  (4u*1024u*1024u + 65536u)
#define OFF_MWIHT   (4u*1024u*1024u + 131072u)
#define OFF_XGM     (8u*1024u*1024u)
#define OFF_WORDS   35651584u
#define OFF_MSGOUT  47185920u
#define OFF_CHOUT   54525952u

typedef _Float16 h2v __attribute__((ext_vector_type(2)));
typedef _Float16 f16x8 __attribute__((ext_vector_type(8)));
typedef float f32x4 __attribute__((ext_vector_type(4)));

__device__ __forceinline__ float bf16_to_f32(unsigned short u){
  union{unsigned int i;float f;}v; v.i=((unsigned int)u)<<16; return v.f;
}
__device__ __forceinline__ unsigned short f32_to_bf16(float f){
  union{float f;unsigned int i;}v; v.f=f;
  unsigned int u=v.i; unsigned int r=(u + 0x7fffu + ((u>>16)&1u))>>16;
  return (unsigned short)r;
}
__device__ __forceinline__ uint32_t pack_h2(float x,float y){
  h2v h; h[0]=(_Float16)x; h[1]=(_Float16)y; uint32_t u; __builtin_memcpy(&u,&h,4); return u;
}
__device__ __forceinline__ unsigned short f32_to_h16u(float f){
  _Float16 h=(_Float16)f; unsigned short u; __builtin_memcpy(&u,&h,2); return u;
}
__device__ __forceinline__ float h16lo(uint32_t u){
  unsigned short s=(unsigned short)(u&0xffffu); _Float16 h; __builtin_memcpy(&h,&s,2); return (float)h;
}
__device__ __forceinline__ float h16hi(uint32_t u){
  unsigned short s=(unsigned short)(u>>16); _Float16 h; __builtin_memcpy(&h,&s,2); return (float)h;
}
__device__ __forceinline__ float dot2(uint32_t a, uint32_t b, float c){
#if __has_builtin(__builtin_amdgcn_fdot2)
  h2v av,bv; __builtin_memcpy(&av,&a,4); __builtin_memcpy(&bv,&b,4);
  return __builtin_amdgcn_fdot2(av,bv,c,false);
#else
  h2v av,bv; __builtin_memcpy(&av,&a,4); __builtin_memcpy(&bv,&b,4);
  return c + (float)av[0]*(float)bv[0] + (float)av[1]*(float)bv[1];
#endif
}
__device__ __forceinline__ float sigmoidf(float x){ return 1.f/(1.f+__expf(-x)); }
__device__ __forceinline__ float tanh_fast(float x){ float e=__expf(2.f*x); return 1.f - 2.f/(e+1.f); }
__device__ __forceinline__ float wave_sum(float v){
  #pragma unroll
  for(int m=32;m>=1;m>>=1) v += __shfl_xor(v,m,64);
  return v;
}
__device__ __forceinline__ float wave_max(float v){
  #pragma unroll
  for(int m=32;m>=1;m>>=1) v = fmaxf(v,__shfl_xor(v,m,64));
  return v;
}
__device__ __forceinline__ f32x4 mfma16(f16x8 a, f16x8 b, f32x4 c){
  return __builtin_amdgcn_mfma_f32_16x16x32_f16(a, b, c, 0, 0, 0);
}

// ---------- dtype sniffer ----------
__global__ void k_flag(const void* emb_raw, int* flag){
  const unsigned short* u=(const unsigned short*)emb_raw;
  int t=threadIdx.x, found=0;
  for(int i=t;i<2048;i+=256){ float v=bf16_to_f32(u[i]); if(fabsf(v)>8.f) found=1; }
  __shared__ int s;
  if(t==0) s=0;
  __syncthreads();
  if(found) atomicOr(&s,1);
  __syncthreads();
  if(t==0) *flag = s;
}

struct ConvArgs { const void* src[25]; int len[25]; int off[25]; };

__global__ void k_convert(ConvArgs a, const int* __restrict__ flag, float* __restrict__ dst){
  int isf32=*flag;
  int idx=blockIdx.x*256+threadIdx.x;
  #pragma unroll 1
  for(int i=0;i<25;i++){
    if(idx < a.len[i]){
      float v = isf32 ? ((const float*)a.src[i])[idx]
                      : bf16_to_f32(((const unsigned short*)a.src[i])[idx]);
      dst[a.off[i]+idx]=v;
      return;
    }
    idx -= a.len[i];
  }
}

// ---------- prep: Wp B-fragments (f16), pool<64> packed pairs, transposed mWih ----------
__global__ void k_prep(const float* __restrict__ cw, unsigned short* __restrict__ wpfrag,
                       uint32_t* __restrict__ wpt2p, float* __restrict__ mWihT){
  int idx=blockIdx.x*256+threadIdx.x;
  if(idx<32768){
    // B-fragment order for mfma_f32_16x16x32_f16: [ks][nt][lane][j]
    int j=idx&7, lane=(idx>>3)&63, nt=(idx>>9)&7, ks=idx>>12;
    int nl=lane&15, q=lane>>4;
    float v = cw[C_WWP + (nt*16+nl)*256 + ks*32 + q*8 + j];
    wpfrag[idx]=f32_to_h16u(v);
  } else if(idx<49152){
    int i=idx-32768; int kp=i>>7, c=i&127; const float* W=cw+C_PWP;
    wpt2p[i]=pack_h2(W[c*256+2*kp], W[c*256+2*kp+1]);
  } else if(idx<245760){
    int iN=idx-49152; int k=iN/768, g=iN-k*768;
    mWihT[iN] = (g<G3) ? cw[C_MWIH_F + g*256 + k] : cw[C_MWIH_B + (g-G3)*256 + k];
  }
}

// ---------- char BiGRU via MFMA (unchanged from round 2) ----------
__global__ __launch_bounds__(512,4) void k_chargru(const int* __restrict__ chars,
    const int* __restrict__ lensp, const float* __restrict__ cw,
    unsigned short* __restrict__ chout){
  int tid=threadIdx.x;
  int w=tid>>6, L=tid&63, nl=L&15, q=L>>4;
  int dir=blockIdx.y;
  int seq0=blockIdx.x*16;
  const float* emb=cw+C_EMB;
  const float* Wih=cw+(dir?C_CWIH_B:C_CWIH_F);
  const float* Whh=cw+(dir?C_CWHH_B:C_CWHH_F);
  const float* bih=cw+(dir?C_CBIH_B:C_CBIH_F);
  const float* bhh=cw+(dir?C_CBHH_B:C_CBHH_F);

  f16x8 bh[3][4], bx[3][2];
  float bias_rz0, bias_rz1, bias_hn, bias_xn;
  #pragma unroll
  for(int i=0;i<3;i++){
    int tile=w+8*i, n=tile*16+nl;
    const float* wr=Whh + n*HDIM;
    #pragma unroll
    for(int c=0;c<4;c++){
      const float4* p=(const float4*)(wr + c*32 + q*8);
      float4 v0=p[0], v1=p[1];
      f16x8 f;
      f[0]=(_Float16)v0.x; f[1]=(_Float16)v0.y; f[2]=(_Float16)v0.z; f[3]=(_Float16)v0.w;
      f[4]=(_Float16)v1.x; f[5]=(_Float16)v1.y; f[6]=(_Float16)v1.z; f[7]=(_Float16)v1.w;
      bh[i][c]=f;
    }
    const float* xr=Wih + n*EDIM;
    #pragma unroll
    for(int c=0;c<2;c++){
      const float4* p=(const float4*)(xr + c*32 + q*8);
      float4 v0=p[0], v1=p[1];
      f16x8 f;
      f[0]=(_Float16)v0.x; f[1]=(_Float16)v0.y; f[2]=(_Float16)v0.z; f[3]=(_Float16)v0.w;
      f[4]=(_Float16)v1.x; f[5]=(_Float16)v1.y; f[6]=(_Float16)v1.z; f[7]=(_Float16)v1.w;
      bx[i][c]=f;
    }
    float bi=bih[n], bo=bhh[n];
    if(i==0) bias_rz0=bi+bo;
    else if(i==1) bias_rz1=bi+bo;
    else { bias_hn=bo; bias_xn=bi; }
  }

  __shared__ int cid[16][CLEN];
  __shared__ int lenS[16];
  __shared__ __align__(16) _Float16 hbuf[16][136];
  __shared__ __align__(16) _Float16 xbuf[2][16][72];
  __shared__ float Grz[16][260];
  __shared__ float Ghn[16][132];
  __shared__ float Gxn[16][132];

  for(int i=tid;i<16*CLEN;i+=512){ int s=i/CLEN, c=i-CLEN*s; cid[s][c]=chars[(seq0+s)*CLEN+c]; }
  if(tid<16) lenS[tid]=lensp[seq0+tid];
  for(int i=tid;i<16*136/2;i+=512) ((uint32_t*)hbuf)[i]=0u;
  __syncthreads();
  {
    int sp=tid>>5, e2=tid&31;
    int t0 = dir ? CLEN-1 : 0;
    const float* er = emb + cid[sp][t0]*EDIM + 2*e2;
    ((uint32_t*)&xbuf[0][sp][0])[e2] = pack_h2(er[0], er[1]);
  }
  __syncthreads();

  float hreg[4]={0.f,0.f,0.f,0.f};
  int colA=w*16+nl, colB=(w+8)*16+nl;
  int jj=tid&127, s0=tid>>7;
  int sp=tid>>5, e2=tid&31;

  for(int step=0; step<CLEN; ++step){
    int t = dir ? CLEN-1-step : step;
    float pf0=0.f, pf1=0.f;
    bool havepf = (step+1 < CLEN);
    if(havepf){
      int tn = dir ? CLEN-2-step : step+1;
      const float* er = emb + cid[sp][tn]*EDIM + 2*e2;
      pf0=er[0]; pf1=er[1];
    }
    f32x4 acc0={bias_rz0,bias_rz0,bias_rz0,bias_rz0};
    f32x4 acc1={bias_rz1,bias_rz1,bias_rz1,bias_rz1};
    f32x4 a2h ={bias_hn,bias_hn,bias_hn,bias_hn};
    f32x4 a2x ={bias_xn,bias_xn,bias_xn,bias_xn};
    const _Float16* hrow=&hbuf[nl][0];
    #pragma unroll
    for(int c=0;c<4;c++){
      f16x8 af = *(const f16x8*)(hrow + c*32 + q*8);
      acc0=mfma16(af, bh[0][c], acc0);
      acc1=mfma16(af, bh[1][c], acc1);
      a2h =mfma16(af, bh[2][c], a2h);
    }
    const _Float16* xrow=&xbuf[step&1][nl][0];
    #pragma unroll
    for(int c=0;c<2;c++){
      f16x8 af = *(const f16x8*)(xrow + c*32 + q*8);
      acc0=mfma16(af, bx[0][c], acc0);
      acc1=mfma16(af, bx[1][c], acc1);
      a2x =mfma16(af, bx[2][c], a2x);
    }
    #pragma unroll
    for(int r=0;r<4;r++){
      int m=q*4+r;
      Grz[m][colA]=acc0[r];
      Grz[m][colB]=acc1[r];
      Ghn[m][colA]=a2h[r];
      Gxn[m][colA]=a2x[r];
    }
    __syncthreads();
    #pragma unroll
    for(int u=0;u<4;u++){
      int s=s0+4*u;
      float r=sigmoidf(Grz[s][jj]);
      float z=sigmoidf(Grz[s][jj+128]);
      float nn=tanh_fast(Gxn[s][jj] + r*Ghn[s][jj]);
      float hnew=(1.f-z)*nn + z*hreg[u];
      bool valid = t < lenS[s];
      float hv = valid ? hnew : hreg[u];
      hreg[u]=hv;
      hbuf[s][jj]=(_Float16)hv;
      chout[((size_t)(seq0+s)*CLEN+t)*256 + dir*HDIM + jj] = valid ? f32_to_h16u(hnew) : (unsigned short)0;
    }
    if(havepf) ((uint32_t*)&xbuf[(step+1)&1][sp][0])[e2] = pack_h2(pf0,pf1);
    __syncthreads();
  }
}

// ---------- word attention pool via MFMA: one word/block, 4 waves ----------
// GEMM: proj[48][128] = out[48][256] @ Wp^T; wave w owns N-tiles {2w,2w+1}, M-tiles 0..2.
__global__ __launch_bounds__(256,4) void k_wpool(const unsigned short* __restrict__ chout,
    const unsigned short* __restrict__ wpfrag, const float* __restrict__ bp,
    const float* __restrict__ ctxv, float* __restrict__ words){
  int n=blockIdx.x, tid=threadIdx.x;
  int w=tid>>6, lane=tid&63, nl=lane&15, q=lane>>4;
  __shared__ __align__(16) _Float16 sa[48][264];   // stride 132 dw == 4 mod 32
  __shared__ float redl[48][4];
  __shared__ float att[48];

  // B fragments (L2-resident, pre-packed in fragment order)
  uint4 bfr[2][8];
  const uint4* wp4=(const uint4*)wpfrag;
  #pragma unroll
  for(int ks=0;ks<8;ks++){
    bfr[0][ks]=wp4[(ks*8+2*w  )*64+lane];
    bfr[1][ks]=wp4[(ks*8+2*w+1)*64+lane];
  }
  // stage A: 48x256 f16 = 1536 uint4
  {
    const uint4* src=(const uint4*)(chout + (size_t)n*48*256);
    #pragma unroll
    for(int i=0;i<6;i++){
      int ii=tid+256*i; int row=ii>>5, c16=ii&31;
      *(uint4*)&sa[row][c16*8]=src[ii];
    }
  }
  __syncthreads();

  f32x4 acc[3][2];
  #pragma unroll
  for(int mt=0;mt<3;mt++){ acc[mt][0]=(f32x4){0,0,0,0}; acc[mt][1]=(f32x4){0,0,0,0}; }
  #pragma unroll
  for(int ks=0;ks<8;ks++){
    f16x8 b0,b1;
    __builtin_memcpy(&b0,&bfr[0][ks],16);
    __builtin_memcpy(&b1,&bfr[1][ks],16);
    #pragma unroll
    for(int mt=0;mt<3;mt++){
      f16x8 af=*(const f16x8*)&sa[mt*16+nl][ks*32+q*8];
      acc[mt][0]=mfma16(af,b0,acc[mt][0]);
      acc[mt][1]=mfma16(af,b1,acc[mt][1]);
    }
  }
  // epilogue: logits[m] = sum_c tanh(proj[m][c]+bp[c])*ctx[c]
  int c0=(2*w)*16+nl, c1=c0+16;
  float bp0=bp[c0], bp1=bp[c1], cv0=ctxv[c0], cv1=ctxv[c1];
  #pragma unroll
  for(int mt=0;mt<3;mt++){
    #pragma unroll
    for(int r=0;r<4;r++){
      float v=tanh_fast(acc[mt][0][r]+bp0)*cv0 + tanh_fast(acc[mt][1][r]+bp1)*cv1;
      v+=__shfl_xor(v,1,64); v+=__shfl_xor(v,2,64);
      v+=__shfl_xor(v,4,64); v+=__shfl_xor(v,8,64);
      if(nl==0) redl[mt*16+q*4+r][w]=v;
    }
  }
  __syncthreads();
  if(tid<64){
    float v=(tid<48)?(redl[tid][0]+redl[tid][1]+redl[tid][2]+redl[tid][3]):-1e30f;
    float mx=wave_max(v);
    float e=(tid<48)?__expf(v-mx):0.f;
    float s=wave_sum(e);
    if(tid<48) att[tid]=e/s;
  }
  __syncthreads();
  float a=0.f;
  #pragma unroll 1
  for(int t=0;t<48;t++) a=fmaf(att[t],(float)sa[t][tid],a);
  words[(size_t)n*256+tid]=a;
}

// ---------- message attention pooling (T=64, 128 blocks, fuses final linear) ----------
__global__ __launch_bounds__(256) void k_mpool(const unsigned short* __restrict__ outp,
    const uint32_t* __restrict__ WpT2, const float* __restrict__ bp,
    const float* __restrict__ ctxv,
    const float* __restrict__ Wout, const float* __restrict__ bout,
    void* dout, const int* __restrict__ flag){
  constexpr int T=64; constexpr int NT=T/2;
  int n=blockIdx.x, tid=threadIdx.x;
  __shared__ uint32_t so[T][128];
  __shared__ float red[T][2];
  __shared__ float att[T];
  __shared__ float msgv[256];
  {
    const uint4* src=(const uint4*)(outp + (size_t)n*T*256);
    uint4* d4=(uint4*)&so[0][0];
    #pragma unroll 1
    for(int i=tid;i<T*32;i+=256) d4[i]=src[i];
  }
  __syncthreads();
  int c=tid&127, tt=tid>>7;
  float acc[NT];
  float bpc=bp[c];
  #pragma unroll
  for(int i=0;i<NT;i++) acc[i]=bpc;
  for(int kp=0;kp<128;kp++){
    uint32_t w2=WpT2[kp*128+c];
    #pragma unroll
    for(int i=0;i<NT;i++) acc[i]=dot2(w2, so[2*i+tt][kp], acc[i]);
  }
  float cv=ctxv[c];
  #pragma unroll
  for(int i=0;i<NT;i++){
    float lg=tanh_fast(acc[i])*cv;
    lg=wave_sum(lg);
    if((tid&63)==0) red[2*i+tt][(tid>>6)&1]=lg;
  }
  __syncthreads();
  if(tid<64){
    float v = red[tid][0]+red[tid][1];
    float m = wave_max(v);
    float e = __expf(v-m);
    float s = wave_sum(e);
    att[tid]=e/s;
  }
  __syncthreads();
  if(tid<128){
    float a0=0.f, a1=0.f;
    #pragma unroll 1
    for(int t=0;t<T;t++){
      uint32_t u=so[t][tid];
      float at=att[t];
      a0=fmaf(at,h16lo(u),a0);
      a1=fmaf(at,h16hi(u),a1);
    }
    msgv[2*tid]=a0; msgv[2*tid+1]=a1;
    if(*flag){ float* mo=(float*)dout + 1024 + n*256; mo[2*tid]=a0; mo[2*tid+1]=a1; }
    else { unsigned short* mo=(unsigned short*)dout + 1024 + n*256;
           mo[2*tid]=f32_to_bf16(a0); mo[2*tid+1]=f32_to_bf16(a1); }
  }
  __syncthreads();
  if(tid<OUTD){
    float a=bout[tid];
    #pragma unroll 1
    for(int k=0;k<256;k++) a=fmaf(msgv[k], Wout[tid*256+k], a);
    if(*flag) ((float*)dout)[n*OUTD+tid]=a;
    else ((unsigned short*)dout)[n*OUTD+tid]=f32_to_bf16(a);
  }
}

// ---------- message input-gate GEMM ----------
__global__ __launch_bounds__(256) void k_msgxg(const float* __restrict__ words,
    const float* __restrict__ mWihT, const float* __restrict__ cw, float* __restrict__ xgm){
  int n0=blockIdx.x*16, tid=threadIdx.x;
  __shared__ float wl[16][256];
  #pragma unroll 1
  for(int i=tid;i<16*256;i+=256) ((float*)wl)[i]=words[(size_t)n0*256+i];
  __syncthreads();
  int g0=tid, g1=tid+256, g2=tid+512;
  float b0 = (g0<G3)? cw[C_MBIH_F+g0] : cw[C_MBIH_B+g0-G3];
  float b1 = (g1<G3)? cw[C_MBIH_F+g1] : cw[C_MBIH_B+g1-G3];
  float b2 = (g2<G3)? cw[C_MBIH_F+g2] : cw[C_MBIH_B+g2-G3];
  float a0[16],a1[16],a2[16];
  #pragma unroll
  for(int w=0;w<16;w++){ a0[w]=b0; a1[w]=b1; a2[w]=b2; }
  for(int k=0;k<256;k++){
    float w0=mWihT[k*768+g0], w1=mWihT[k*768+g1], w2v=mWihT[k*768+g2];
    #pragma unroll
    for(int w=0;w<16;w++){
      float x=wl[w][k];
      a0[w]=fmaf(x,w0,a0[w]); a1[w]=fmaf(x,w1,a1[w]); a2[w]=fmaf(x,w2v,a2[w]);
    }
  }
  for(int w=0;w<16;w++){
    int n=n0+w;
    { int g=g0; float v=a0[w]; if(g<G3) xgm[(size_t)n*G3+g]=v; else xgm[(size_t)NW*G3+(size_t)n*G3+g-G3]=v; }
    { int g=g1; float v=a1[w]; if(g<G3) xgm[(size_t)n*G3+g]=v; else xgm[(size_t)NW*G3+(size_t)n*G3+g-G3]=v; }
    { int g=g2; float v=a2[w]; if(g<G3) xgm[(size_t)n*G3+g]=v; else xgm[(size_t)NW*G3+(size_t)n*G3+g-G3]=v; }
  }
}

// ---------- message BiGRU ----------
__global__ __launch_bounds__(384) void k_msggru(const float* __restrict__ cw,
    const float* __restrict__ xgm, unsigned short* __restrict__ msg_out){
  int dir=blockIdx.y, b=blockIdx.x, tid=threadIdx.x;
  const float* Whh=cw+(dir?C_MWHH_B:C_MWHH_F);
  const float* bhh=cw+(dir?C_MBHH_B:C_MBHH_F);
  const float* xg = xgm + (size_t)dir*NW*G3;
  uint32_t whh[64];
  {
    const float4* h4=(const float4*)(Whh + tid*HDIM);
    #pragma unroll
    for(int i=0;i<32;i++){ float4 v=h4[i]; whh[2*i]=pack_h2(v.x,v.y); whh[2*i+1]=pack_h2(v.z,v.w); }
  }
  float bhh_g=bhh[tid];
  __shared__ __align__(16) unsigned short hh[HDIM];
  __shared__ float rr[HDIM], zz[HDIM], xns[HDIM], hns[HDIM];
  if(tid<64) ((uint32_t*)hh)[tid]=0u;
  float hreg=0.f;
  __syncthreads();
  int j=tid&127, gt=tid>>7;
  for(int step=0;step<WRD;step++){
    int w = dir ? (WRD-1-step) : step;
    float xacc = xg[(size_t)(b*WRD+w)*G3 + tid];
    float ha=bhh_g;
    const uint4* hp=(const uint4*)hh;
    #pragma unroll
    for(int q=0;q<16;q++){ uint4 v=hp[q];
      ha=dot2(whh[4*q+0],v.x,ha); ha=dot2(whh[4*q+1],v.y,ha);
      ha=dot2(whh[4*q+2],v.z,ha); ha=dot2(whh[4*q+3],v.w,ha); }
    if(gt==0)      rr[j]=sigmoidf(xacc+ha);
    else if(gt==1) zz[j]=sigmoidf(xacc+ha);
    else { xns[j]=xacc; hns[j]=ha; }
    __syncthreads();
    if(tid<HDIM){
      float r=rr[tid], z=zz[tid];
      float nn=tanh_fast(xns[tid]+r*hns[tid]);
      float hnew=(1.f-z)*nn + z*hreg;
      hreg=hnew;
      hh[tid]=f32_to_h16u(hnew);
      msg_out[(size_t)(b*WRD+w)*256 + dir*HDIM + tid]=f32_to_h16u(hnew);
    }
    __syncthreads();
  }
}

extern "C" void kernel_launch(void* const* d_in, const int* in_sizes, int n_in,
                              void* d_out, int out_size, void* d_ws, size_t ws_size,
                              hipStream_t stream){
  (void)in_sizes; (void)n_in; (void)out_size; (void)ws_size;
  char* ws=(char*)d_ws;
  int* flag=(int*)(ws+OFF_FLAG);
  float* canon=(float*)(ws+OFF_CANON);
  unsigned short* wpfrag=(unsigned short*)(ws+OFF_WPFRAG);
  uint32_t* wpt2p=(uint32_t*)(ws+OFF_WPT2_P);
  float* mWihT=(float*)(ws+OFF_MWIHT);
  float* xgm=(float*)(ws+OFF_XGM);
  float* words=(float*)(ws+OFF_WORDS);
  unsigned short* msgout=(unsigned short*)(ws+OFF_MSGOUT);
  unsigned short* chout=(unsigned short*)(ws+OFF_CHOUT);
  const int* chars=(const int*)d_in[0];
  const int* lensp=(const int*)d_in[1];

  hipLaunchKernelGGL(k_flag, dim3(1), dim3(256), 0, stream, d_in[2], flag);

  ConvArgs ca;
  static const int clen_[25]={16384,24576,49152,384,384,24576,49152,384,384,
                              98304,49152,768,768,98304,49152,768,768,
                              32768,128,128,32768,128,128,2048,8};
  int off=0;
  for(int i=0;i<25;i++){ ca.src[i]=d_in[i+2]; ca.len[i]=clen_[i]; ca.off[i]=off; off+=clen_[i]; }
  hipLaunchKernelGGL(k_convert, dim3((C_TOTAL+255)/256), dim3(256), 0, stream, ca, flag, canon);
  hipLaunchKernelGGL(k_prep, dim3(960), dim3(256), 0, stream, canon, wpfrag, wpt2p, mWihT);
  hipLaunchKernelGGL(k_chargru, dim3(NW/16,2), dim3(512), 0, stream, chars, lensp, canon, chout);
  hipLaunchKernelGGL(k_wpool, dim3(NW), dim3(256), 0, stream, chout, wpfrag,
                     canon+C_WBP, canon+C_WCTX, words);
  hipLaunchKernelGGL(k_msgxg, dim3(NW/16), dim3(256), 0, stream, words, mWihT, canon, xgm);
  hipLaunchKernelGGL(k_msggru, dim3(BATCH,2), dim3(384), 0, stream, canon, xgm, msgout);
  hipLaunchKernelGGL(k_mpool, dim3(BATCH), dim3(256), 0, stream, msgout, wpt2p,
                     canon+C_PBP, canon+C_PCTX,
                     canon+C_WOUT, canon+C_BOUT, d_out, flag);
}

// Round 4
// 667.092 us; speedup vs baseline: 4.2672x; 1.0987x over previous
//
#include <hip/hip_runtime.h>
#include <stdint.h>
#include <stddef.h>

#define NCH   256
#define EDIM  64
#define HDIM  128
#define G3    384
#define BATCH 128
#define WRD   64
#define CLEN  48
#define NW    8192
#define OUTD  8

// ---- canonical fp32 weight offsets (element units) ----
#define C_EMB     0
#define C_CWIH_F  16384
#define C_CWHH_F  40960
#define C_CBIH_F  90112
#define C_CBHH_F  90496
#define C_CWIH_B  90880
#define C_CWHH_B  115456
#define C_CBIH_B  164608
#define C_CBHH_B  164992
#define C_MWIH_F  165376
#define C_MWHH_F  263680
#define C_MBIH_F  312832
#define C_MBHH_F  313600
#define C_MWIH_B  314368
#define C_MWHH_B  412672
#define C_MBIH_B  461824
#define C_MBHH_B  462592
#define C_WWP     463360
#define C_WBP     496128
#define C_WCTX    496256
#define C_PWP     496384
#define C_PBP     529152
#define C_PCTX    529280
#define C_WOUT    529408
#define C_BOUT    531456
#define C_TOTAL   531464

// ---- ws byte offsets ----
#define OFF_FLAG    0u
#define OFF_CANON   1024u
#define OFF_WPFRAG  (4u*1024u*1024u)              // 32768 f16 = 65536 B
#define OFF_WPT2_P  (4u*1024u*1024u + 65536u)
#define OFF_MWIHT   (4u*1024u*1024u + 131072u)
#define OFF_XGM     (8u*1024u*1024u)
#define OFF_WORDS   35651584u
#define OFF_MSGOUT  47185920u
#define OFF_CHOUT   54525952u

typedef _Float16 h2v __attribute__((ext_vector_type(2)));
typedef _Float16 f16x8 __attribute__((ext_vector_type(8)));
typedef float f32x4 __attribute__((ext_vector_type(4)));

__device__ __forceinline__ float bf16_to_f32(unsigned short u){
  union{unsigned int i;float f;}v; v.i=((unsigned int)u)<<16; return v.f;
}
__device__ __forceinline__ unsigned short f32_to_bf16(float f){
  union{float f;unsigned int i;}v; v.f=f;
  unsigned int u=v.i; unsigned int r=(u + 0x7fffu + ((u>>16)&1u))>>16;
  return (unsigned short)r;
}
__device__ __forceinline__ uint32_t pack_h2(float x,float y){
  h2v h; h[0]=(_Float16)x; h[1]=(_Float16)y; uint32_t u; __builtin_memcpy(&u,&h,4); return u;
}
__device__ __forceinline__ unsigned short f32_to_h16u(float f){
  _Float16 h=(_Float16)f; unsigned short u; __builtin_memcpy(&u,&h,2); return u;
}
__device__ __forceinline__ float h16lo(uint32_t u){
  unsigned short s=(unsigned short)(u&0xffffu); _Float16 h; __builtin_memcpy(&h,&s,2); return (float)h;
}
__device__ __forceinline__ float h16hi(uint32_t u){
  unsigned short s=(unsigned short)(u>>16); _Float16 h; __builtin_memcpy(&h,&s,2); return (float)h;
}
__device__ __forceinline__ float dot2(uint32_t a, uint32_t b, float c){
#if __has_builtin(__builtin_amdgcn_fdot2)
  h2v av,bv; __builtin_memcpy(&av,&a,4); __builtin_memcpy(&bv,&b,4);
  return __builtin_amdgcn_fdot2(av,bv,c,false);
#else
  h2v av,bv; __builtin_memcpy(&av,&a,4); __builtin_memcpy(&bv,&b,4);
  return c + (float)av[0]*(float)bv[0] + (float)av[1]*(float)bv[1];
#endif
}
__device__ __forceinline__ float sigmoidf(float x){ return 1.f/(1.f+__expf(-x)); }
__device__ __forceinline__ float tanh_fast(float x){ float e=__expf(2.f*x); return 1.f - 2.f/(e+1.f); }
__device__ __forceinline__ float wave_sum(float v){
  #pragma unroll
  for(int m=32;m>=1;m>>=1) v += __shfl_xor(v,m,64);
  return v;
}
__device__ __forceinline__ float wave_max(float v){
  #pragma unroll
  for(int m=32;m>=1;m>>=1) v = fmaxf(v,__shfl_xor(v,m,64));
  return v;
}
__device__ __forceinline__ f32x4 mfma16(f16x8 a, f16x8 b, f32x4 c){
  return __builtin_amdgcn_mfma_f32_16x16x32_f16(a, b, c, 0, 0, 0);
}

// ---------- dtype sniffer ----------
__global__ void k_flag(const void* emb_raw, int* flag){
  const unsigned short* u=(const unsigned short*)emb_raw;
  int t=threadIdx.x, found=0;
  for(int i=t;i<2048;i+=256){ float v=bf16_to_f32(u[i]); if(fabsf(v)>8.f) found=1; }
  __shared__ int s;
  if(t==0) s=0;
  __syncthreads();
  if(found) atomicOr(&s,1);
  __syncthreads();
  if(t==0) *flag = s;
}

struct ConvArgs { const void* src[25]; int len[25]; int off[25]; };

__global__ void k_convert(ConvArgs a, const int* __restrict__ flag, float* __restrict__ dst){
  int isf32=*flag;
  int idx=blockIdx.x*256+threadIdx.x;
  #pragma unroll 1
  for(int i=0;i<25;i++){
    if(idx < a.len[i]){
      float v = isf32 ? ((const float*)a.src[i])[idx]
                      : bf16_to_f32(((const unsigned short*)a.src[i])[idx]);
      dst[a.off[i]+idx]=v;
      return;
    }
    idx -= a.len[i];
  }
}

// ---------- prep: Wp B-fragments (f16), pool<64> packed pairs, transposed mWih ----------
__global__ void k_prep(const float* __restrict__ cw, unsigned short* __restrict__ wpfrag,
                       uint32_t* __restrict__ wpt2p, float* __restrict__ mWihT){
  int idx=blockIdx.x*256+threadIdx.x;
  if(idx<32768){
    int j=idx&7, lane=(idx>>3)&63, nt=(idx>>9)&7, ks=idx>>12;
    int nl=lane&15, q=lane>>4;
    float v = cw[C_WWP + (nt*16+nl)*256 + ks*32 + q*8 + j];
    wpfrag[idx]=f32_to_h16u(v);
  } else if(idx<49152){
    int i=idx-32768; int kp=i>>7, c=i&127; const float* W=cw+C_PWP;
    wpt2p[i]=pack_h2(W[c*256+2*kp], W[c*256+2*kp+1]);
  } else if(idx<245760){
    int iN=idx-49152; int k=iN/768, g=iN-k*768;
    mWihT[iN] = (g<G3) ? cw[C_MWIH_F + g*256 + k] : cw[C_MWIH_B + (g-G3)*256 + k];
  }
}

// ---------- char BiGRU via MFMA with in-register GRU update ----------
// 16 seqs/block, 8 waves. Wave w owns gate-tiles {w,w+8,w+16} => same col c=16w+nl
// in each of r/z/n gate groups, so acc0=r, acc1=z, a2h=hn, a2x=xn for identical
// (seq=q*4+reg, c) — the elementwise update runs entirely in registers.
__global__ __launch_bounds__(512,4) void k_chargru(const int* __restrict__ chars,
    const int* __restrict__ lensp, const float* __restrict__ cw,
    unsigned short* __restrict__ chout){
  int tid=threadIdx.x;
  int w=tid>>6, L=tid&63, nl=L&15, q=L>>4;
  int dir=blockIdx.y;
  int seq0=blockIdx.x*16;
  const float* emb=cw+C_EMB;
  const float* Wih=cw+(dir?C_CWIH_B:C_CWIH_F);
  const float* Whh=cw+(dir?C_CWHH_B:C_CWHH_F);
  const float* bih=cw+(dir?C_CBIH_B:C_CBIH_F);
  const float* bhh=cw+(dir?C_CBHH_B:C_CBHH_F);

  f16x8 bh[3][4], bx[3][2];
  float bias_r, bias_z, bias_hn, bias_xn;
  #pragma unroll
  for(int i=0;i<3;i++){
    int tile=w+8*i, n=tile*16+nl;
    const float* wr=Whh + n*HDIM;
    #pragma unroll
    for(int c=0;c<4;c++){
      const float4* p=(const float4*)(wr + c*32 + q*8);
      float4 v0=p[0], v1=p[1];
      f16x8 f;
      f[0]=(_Float16)v0.x; f[1]=(_Float16)v0.y; f[2]=(_Float16)v0.z; f[3]=(_Float16)v0.w;
      f[4]=(_Float16)v1.x; f[5]=(_Float16)v1.y; f[6]=(_Float16)v1.z; f[7]=(_Float16)v1.w;
      bh[i][c]=f;
    }
    const float* xr=Wih + n*EDIM;
    #pragma unroll
    for(int c=0;c<2;c++){
      const float4* p=(const float4*)(xr + c*32 + q*8);
      float4 v0=p[0], v1=p[1];
      f16x8 f;
      f[0]=(_Float16)v0.x; f[1]=(_Float16)v0.y; f[2]=(_Float16)v0.z; f[3]=(_Float16)v0.w;
      f[4]=(_Float16)v1.x; f[5]=(_Float16)v1.y; f[6]=(_Float16)v1.z; f[7]=(_Float16)v1.w;
      bx[i][c]=f;
    }
    float bi=bih[n], bo=bhh[n];
    if(i==0) bias_r=bi+bo;
    else if(i==1) bias_z=bi+bo;
    else { bias_hn=bo; bias_xn=bi; }
  }

  __shared__ int cid[16][CLEN];
  __shared__ int lenS[16];
  __shared__ __align__(16) _Float16 hbuf[2][16][136];  // double-buffered h state
  __shared__ __align__(16) _Float16 xbuf[2][16][72];

  for(int i=tid;i<16*CLEN;i+=512){ int s=i/CLEN, c=i-CLEN*s; cid[s][c]=chars[(seq0+s)*CLEN+c]; }
  if(tid<16) lenS[tid]=lensp[seq0+tid];
  for(int i=tid;i<16*136/2;i+=512) ((uint32_t*)&hbuf[0][0][0])[i]=0u;
  __syncthreads();
  {
    int sp=tid>>5, e2=tid&31;
    int t0 = dir ? CLEN-1 : 0;
    const float* er = emb + cid[sp][t0]*EDIM + 2*e2;
    ((uint32_t*)&xbuf[0][sp][0])[e2] = pack_h2(er[0], er[1]);
  }
  int lenq[4];
  #pragma unroll
  for(int r=0;r<4;r++) lenq[r]=lenS[q*4+r];
  int lenp=lenS[tid>>5];
  __syncthreads();

  float hreg[4]={0.f,0.f,0.f,0.f};
  int c16=w*16+nl;
  int sp=tid>>5, e2=tid&31;
  int sw=tid>>5, aw=tid&31;

  for(int step=0; step<CLEN; ++step){
    int t = dir ? CLEN-1-step : step;
    int p = step&1;
    float pf0=0.f, pf1=0.f;
    bool havepf = (step+1 < CLEN);
    if(havepf){
      int tn = dir ? CLEN-2-step : step+1;
      const float* er = emb + cid[sp][tn]*EDIM + 2*e2;
      pf0=er[0]; pf1=er[1];
    }
    // ---- MFMA phase ----
    f32x4 acc0={bias_r,bias_r,bias_r,bias_r};
    f32x4 acc1={bias_z,bias_z,bias_z,bias_z};
    f32x4 a2h ={bias_hn,bias_hn,bias_hn,bias_hn};
    f32x4 a2x ={bias_xn,bias_xn,bias_xn,bias_xn};
    const _Float16* hrow=&hbuf[p][nl][0];
    #pragma unroll
    for(int c=0;c<4;c++){
      f16x8 af = *(const f16x8*)(hrow + c*32 + q*8);
      acc0=mfma16(af, bh[0][c], acc0);
      acc1=mfma16(af, bh[1][c], acc1);
      a2h =mfma16(af, bh[2][c], a2h);
    }
    const _Float16* xrow=&xbuf[p][nl][0];
    #pragma unroll
    for(int c=0;c<2;c++){
      f16x8 af = *(const f16x8*)(xrow + c*32 + q*8);
      acc0=mfma16(af, bx[0][c], acc0);
      acc1=mfma16(af, bx[1][c], acc1);
      a2x =mfma16(af, bx[2][c], a2x);
    }
    // ---- in-register GRU update; write new h into the other buffer ----
    #pragma unroll
    for(int r=0;r<4;r++){
      float rg=sigmoidf(acc0[r]);
      float zg=sigmoidf(acc1[r]);
      float nn=tanh_fast(a2x[r] + rg*a2h[r]);
      float hnew=zg*(hreg[r]-nn)+nn;
      bool valid = t < lenq[r];
      float hv = valid ? hnew : hreg[r];
      hreg[r]=hv;
      hbuf[p^1][q*4+r][c16]=(_Float16)hv;
    }
    __syncthreads();
    // ---- coalesced chout writer + x prefetch ----
    {
      const uint32_t* hr=(const uint32_t*)&hbuf[p^1][sw][0];
      uint32_t d0=hr[2*aw], d1=hr[2*aw+1];
      if(t>=lenp){ d0=0u; d1=0u; }
      *(uint2*)(chout + ((size_t)(seq0+sw)*CLEN+t)*256 + dir*HDIM + 4*aw) = make_uint2(d0,d1);
    }
    if(havepf) ((uint32_t*)&xbuf[p^1][sp][0])[e2] = pack_h2(pf0,pf1);
    __syncthreads();
  }
}

// ---------- word attention pool via MFMA: one word/block, 4 waves ----------
__global__ __launch_bounds__(256,4) void k_wpool(const unsigned short* __restrict__ chout,
    const unsigned short* __restrict__ wpfrag, const float* __restrict__ bp,
    const float* __restrict__ ctxv, float* __restrict__ words){
  int n=blockIdx.x, tid=threadIdx.x;
  int w=tid>>6, lane=tid&63, nl=lane&15, q=lane>>4;
  __shared__ __align__(16) _Float16 sa[48][264];
  __shared__ float redl[48][4];
  __shared__ float att[48];

  uint4 bfr[2][8];
  const uint4* wp4=(const uint4*)wpfrag;
  #pragma unroll
  for(int ks=0;ks<8;ks++){
    bfr[0][ks]=wp4[(ks*8+2*w  )*64+lane];
    bfr[1][ks]=wp4[(ks*8+2*w+1)*64+lane];
  }
  {
    const uint4* src=(const uint4*)(chout + (size_t)n*48*256);
    #pragma unroll
    for(int i=0;i<6;i++){
      int ii=tid+256*i; int row=ii>>5, c16=ii&31;
      *(uint4*)&sa[row][c16*8]=src[ii];
    }
  }
  __syncthreads();

  f32x4 acc[3][2];
  #pragma unroll
  for(int mt=0;mt<3;mt++){ acc[mt][0]=(f32x4){0,0,0,0}; acc[mt][1]=(f32x4){0,0,0,0}; }
  #pragma unroll
  for(int ks=0;ks<8;ks++){
    f16x8 b0,b1;
    __builtin_memcpy(&b0,&bfr[0][ks],16);
    __builtin_memcpy(&b1,&bfr[1][ks],16);
    #pragma unroll
    for(int mt=0;mt<3;mt++){
      f16x8 af=*(const f16x8*)&sa[mt*16+nl][ks*32+q*8];
      acc[mt][0]=mfma16(af,b0,acc[mt][0]);
      acc[mt][1]=mfma16(af,b1,acc[mt][1]);
    }
  }
  int c0=(2*w)*16+nl, c1=c0+16;
  float bp0=bp[c0], bp1=bp[c1], cv0=ctxv[c0], cv1=ctxv[c1];
  #pragma unroll
  for(int mt=0;mt<3;mt++){
    #pragma unroll
    for(int r=0;r<4;r++){
      float v=tanh_fast(acc[mt][0][r]+bp0)*cv0 + tanh_fast(acc[mt][1][r]+bp1)*cv1;
      v+=__shfl_xor(v,1,64); v+=__shfl_xor(v,2,64);
      v+=__shfl_xor(v,4,64); v+=__shfl_xor(v,8,64);
      if(nl==0) redl[mt*16+q*4+r][w]=v;
    }
  }
  __syncthreads();
  if(tid<64){
    float v=(tid<48)?(redl[tid][0]+redl[tid][1]+redl[tid][2]+redl[tid][3]):-1e30f;
    float mx=wave_max(v);
    float e=(tid<48)?__expf(v-mx):0.f;
    float s=wave_sum(e);
    if(tid<48) att[tid]=e/s;
  }
  __syncthreads();
  float a=0.f;
  #pragma unroll 1
  for(int t=0;t<48;t++) a=fmaf(att[t],(float)sa[t][tid],a);
  words[(size_t)n*256+tid]=a;
}

// ---------- message attention pooling (T=64, fuses final linear) ----------
__global__ __launch_bounds__(256) void k_mpool(const unsigned short* __restrict__ outp,
    const uint32_t* __restrict__ WpT2, const float* __restrict__ bp,
    const float* __restrict__ ctxv,
    const float* __restrict__ Wout, const float* __restrict__ bout,
    void* dout, const int* __restrict__ flag){
  constexpr int T=64; constexpr int NT=T/2;
  int n=blockIdx.x, tid=threadIdx.x;
  __shared__ uint32_t so[T][128];
  __shared__ float red[T][2];
  __shared__ float att[T];
  __shared__ float msgv[256];
  {
    const uint4* src=(const uint4*)(outp + (size_t)n*T*256);
    uint4* d4=(uint4*)&so[0][0];
    #pragma unroll 1
    for(int i=tid;i<T*32;i+=256) d4[i]=src[i];
  }
  __syncthreads();
  int c=tid&127, tt=tid>>7;
  float acc[NT];
  float bpc=bp[c];
  #pragma unroll
  for(int i=0;i<NT;i++) acc[i]=bpc;
  for(int kp=0;kp<128;kp++){
    uint32_t w2=WpT2[kp*128+c];
    #pragma unroll
    for(int i=0;i<NT;i++) acc[i]=dot2(w2, so[2*i+tt][kp], acc[i]);
  }
  float cv=ctxv[c];
  #pragma unroll
  for(int i=0;i<NT;i++){
    float lg=tanh_fast(acc[i])*cv;
    lg=wave_sum(lg);
    if((tid&63)==0) red[2*i+tt][(tid>>6)&1]=lg;
  }
  __syncthreads();
  if(tid<64){
    float v = red[tid][0]+red[tid][1];
    float m = wave_max(v);
    float e = __expf(v-m);
    float s = wave_sum(e);
    att[tid]=e/s;
  }
  __syncthreads();
  if(tid<128){
    float a0=0.f, a1=0.f;
    #pragma unroll 1
    for(int t=0;t<T;t++){
      uint32_t u=so[t][tid];
      float at=att[t];
      a0=fmaf(at,h16lo(u),a0);
      a1=fmaf(at,h16hi(u),a1);
    }
    msgv[2*tid]=a0; msgv[2*tid+1]=a1;
    if(*flag){ float* mo=(float*)dout + 1024 + n*256; mo[2*tid]=a0; mo[2*tid+1]=a1; }
    else { unsigned short* mo=(unsigned short*)dout + 1024 + n*256;
           mo[2*tid]=f32_to_bf16(a0); mo[2*tid+1]=f32_to_bf16(a1); }
  }
  __syncthreads();
  if(tid<OUTD){
    float a=bout[tid];
    #pragma unroll 1
    for(int k=0;k<256;k++) a=fmaf(msgv[k], Wout[tid*256+k], a);
    if(*flag) ((float*)dout)[n*OUTD+tid]=a;
    else ((unsigned short*)dout)[n*OUTD+tid]=f32_to_bf16(a);
  }
}

// ---------- message input-gate GEMM ----------
__global__ __launch_bounds__(256) void k_msgxg(const float* __restrict__ words,
    const float* __restrict__ mWihT, const float* __restrict__ cw, float* __restrict__ xgm){
  int n0=blockIdx.x*16, tid=threadIdx.x;
  __shared__ float wl[16][256];
  #pragma unroll 1
  for(int i=tid;i<16*256;i+=256) ((float*)wl)[i]=words[(size_t)n0*256+i];
  __syncthreads();
  int g0=tid, g1=tid+256, g2=tid+512;
  float b0 = (g0<G3)? cw[C_MBIH_F+g0] : cw[C_MBIH_B+g0-G3];
  float b1 = (g1<G3)? cw[C_MBIH_F+g1] : cw[C_MBIH_B+g1-G3];
  float b2 = (g2<G3)? cw[C_MBIH_F+g2] : cw[C_MBIH_B+g2-G3];
  float a0[16],a1[16],a2[16];
  #pragma unroll
  for(int w=0;w<16;w++){ a0[w]=b0; a1[w]=b1; a2[w]=b2; }
  for(int k=0;k<256;k++){
    float w0=mWihT[k*768+g0], w1=mWihT[k*768+g1], w2v=mWihT[k*768+g2];
    #pragma unroll
    for(int w=0;w<16;w++){
      float x=wl[w][k];
      a0[w]=fmaf(x,w0,a0[w]); a1[w]=fmaf(x,w1,a1[w]); a2[w]=fmaf(x,w2v,a2[w]);
    }
  }
  for(int w=0;w<16;w++){
    int n=n0+w;
    { int g=g0; float v=a0[w]; if(g<G3) xgm[(size_t)n*G3+g]=v; else xgm[(size_t)NW*G3+(size_t)n*G3+g-G3]=v; }
    { int g=g1; float v=a1[w]; if(g<G3) xgm[(size_t)n*G3+g]=v; else xgm[(size_t)NW*G3+(size_t)n*G3+g-G3]=v; }
    { int g=g2; float v=a2[w]; if(g<G3) xgm[(size_t)n*G3+g]=v; else xgm[(size_t)NW*G3+(size_t)n*G3+g-G3]=v; }
  }
}

// ---------- message BiGRU ----------
__global__ __launch_bounds__(384) void k_msggru(const float* __restrict__ cw,
    const float* __restrict__ xgm, unsigned short* __restrict__ msg_out){
  int dir=blockIdx.y, b=blockIdx.x, tid=threadIdx.x;
  const float* Whh=cw+(dir?C_MWHH_B:C_MWHH_F);
  const float* bhh=cw+(dir?C_MBHH_B:C_MBHH_F);
  const float* xg = xgm + (size_t)dir*NW*G3;
  uint32_t whh[64];
  {
    const float4* h4=(const float4*)(Whh + tid*HDIM);
    #pragma unroll
    for(int i=0;i<32;i++){ float4 v=h4[i]; whh[2*i]=pack_h2(v.x,v.y); whh[2*i+1]=pack_h2(v.z,v.w); }
  }
  float bhh_g=bhh[tid];
  __shared__ __align__(16) unsigned short hh[HDIM];
  __shared__ float rr[HDIM], zz[HDIM], xns[HDIM], hns[HDIM];
  if(tid<64) ((uint32_t*)hh)[tid]=0u;
  float hreg=0.f;
  __syncthreads();
  int j=tid&127, gt=tid>>7;
  for(int step=0;step<WRD;step++){
    int w = dir ? (WRD-1-step) : step;
    float xacc = xg[(size_t)(b*WRD+w)*G3 + tid];
    float ha=bhh_g;
    const uint4* hp=(const uint4*)hh;
    #pragma unroll
    for(int q=0;q<16;q++){ uint4 v=hp[q];
      ha=dot2(whh[4*q+0],v.x,ha); ha=dot2(whh[4*q+1],v.y,ha);
      ha=dot2(whh[4*q+2],v.z,ha); ha=dot2(whh[4*q+3],v.w,ha); }
    if(gt==0)      rr[j]=sigmoidf(xacc+ha);
    else if(gt==1) zz[j]=sigmoidf(xacc+ha);
    else { xns[j]=xacc; hns[j]=ha; }
    __syncthreads();
    if(tid<HDIM){
      float r=rr[tid], z=zz[tid];
      float nn=tanh_fast(xns[tid]+r*hns[tid]);
      float hnew=(1.f-z)*nn + z*hreg;
      hreg=hnew;
      hh[tid]=f32_to_h16u(hnew);
      msg_out[(size_t)(b*WRD+w)*256 + dir*HDIM + tid]=f32_to_h16u(hnew);
    }
    __syncthreads();
  }
}

extern "C" void kernel_launch(void* const* d_in, const int* in_sizes, int n_in,
                              void* d_out, int out_size, void* d_ws, size_t ws_size,
                              hipStream_t stream){
  (void)in_sizes; (void)n_in; (void)out_size; (void)ws_size;
  char* ws=(char*)d_ws;
  int* flag=(int*)(ws+OFF_FLAG);
  float* canon=(float*)(ws+OFF_CANON);
  unsigned short* wpfrag=(unsigned short*)(ws+OFF_WPFRAG);
  uint32_t* wpt2p=(uint32_t*)(ws+OFF_WPT2_P);
  float* mWihT=(float*)(ws+OFF_MWIHT);
  float* xgm=(float*)(ws+OFF_XGM);
  float* words=(float*)(ws+OFF_WORDS);
  unsigned short* msgout=(unsigned short*)(ws+OFF_MSGOUT);
  unsigned short* chout=(unsigned short*)(ws+OFF_CHOUT);
  const int* chars=(const int*)d_in[0];
  const int* lensp=(const int*)d_in[1];

  hipLaunchKernelGGL(k_flag, dim3(1), dim3(256), 0, stream, d_in[2], flag);

  ConvArgs ca;
  static const int clen_[25]={16384,24576,49152,384,384,24576,49152,384,384,
                              98304,49152,768,768,98304,49152,768,768,
                              32768,128,128,32768,128,128,2048,8};
  int off=0;
  for(int i=0;i<25;i++){ ca.src[i]=d_in[i+2]; ca.len[i]=clen_[i]; ca.off[i]=off; off+=clen_[i]; }
  hipLaunchKernelGGL(k_convert, dim3((C_TOTAL+255)/256), dim3(256), 0, stream, ca, flag, canon);
  hipLaunchKernelGGL(k_prep, dim3(960), dim3(256), 0, stream, canon, wpfrag, wpt2p, mWihT);
  hipLaunchKernelGGL(k_chargru, dim3(NW/16,2), dim3(512), 0, stream, chars, lensp, canon, chout);
  hipLaunchKernelGGL(k_wpool, dim3(NW), dim3(256), 0, stream, chout, wpfrag,
                     canon+C_WBP, canon+C_WCTX, words);
  hipLaunchKernelGGL(k_msgxg, dim3(NW/16), dim3(256), 0, stream, words, mWihT, canon, xgm);
  hipLaunchKernelGGL(k_msggru, dim3(BATCH,2), dim3(384), 0, stream, canon, xgm, msgout);
  hipLaunchKernelGGL(k_mpool, dim3(BATCH), dim3(256), 0, stream, msgout, wpt2p,
                     canon+C_PBP, canon+C_PCTX,
                     canon+C_WOUT, canon+C_BOUT, d_out, flag);
}

// Round 5
// 602.418 us; speedup vs baseline: 4.7253x; 1.1074x over previous
//
#include <hip/hip_runtime.h>
#include <stdint.h>
#include <stddef.h>

#define NCH   256
#define EDIM  64
#define HDIM  128
#define G3    384
#define BATCH 128
#define WRD   64
#define CLEN  48
#define NW    8192
#define OUTD  8

// ---- canonical fp32 weight offsets (element units) ----
#define C_EMB     0
#define C_CWIH_F  16384
#define C_CWHH_F  40960
#define C_CBIH_F  90112
#define C_CBHH_F  90496
#define C_CWIH_B  90880
#define C_CWHH_B  115456
#define C_CBIH_B  164608
#define C_CBHH_B  164992
#define C_MWIH_F  165376
#define C_MWHH_F  263680
#define C_MBIH_F  312832
#define C_MBHH_F  313600
#define C_MWIH_B  314368
#define C_MWHH_B  412672
#define C_MBIH_B  461824
#define C_MBHH_B  462592
#define C_WWP     463360
#define C_WBP     496128
#define C_WCTX    496256
#define C_PWP     496384
#define C_PBP     529152
#define C_PCTX    529280
#define C_WOUT    529408
#define C_BOUT    531456
#define C_TOTAL   531464

// ---- ws byte offsets ----
#define OFF_FLAG    0u
#define OFF_CANON   1024u
#define OFF_WPFRAG  (4u*1024u*1024u)              // 32768 f16 = 65536 B
#define OFF_WPT2_P  (4u*1024u*1024u + 65536u)
#define OFF_MWIHT   (4u*1024u*1024u + 131072u)    // 196608 f32 = 786432 B
#define OFF_XGT     5111808u                       // 2*256*384 f32 = 786432 B
#define OFF_XGM     (8u*1024u*1024u)
#define OFF_WORDS   35651584u
#define OFF_MSGOUT  47185920u
#define OFF_CHOUT   54525952u

typedef _Float16 h2v __attribute__((ext_vector_type(2)));
typedef _Float16 f16x8 __attribute__((ext_vector_type(8)));
typedef float f32x4 __attribute__((ext_vector_type(4)));

__device__ __forceinline__ float bf16_to_f32(unsigned short u){
  union{unsigned int i;float f;}v; v.i=((unsigned int)u)<<16; return v.f;
}
__device__ __forceinline__ unsigned short f32_to_bf16(float f){
  union{float f;unsigned int i;}v; v.f=f;
  unsigned int u=v.i; unsigned int r=(u + 0x7fffu + ((u>>16)&1u))>>16;
  return (unsigned short)r;
}
__device__ __forceinline__ uint32_t pack_h2(float x,float y){
  h2v h; h[0]=(_Float16)x; h[1]=(_Float16)y; uint32_t u; __builtin_memcpy(&u,&h,4); return u;
}
__device__ __forceinline__ unsigned short f32_to_h16u(float f){
  _Float16 h=(_Float16)f; unsigned short u; __builtin_memcpy(&u,&h,2); return u;
}
__device__ __forceinline__ float h16lo(uint32_t u){
  unsigned short s=(unsigned short)(u&0xffffu); _Float16 h; __builtin_memcpy(&h,&s,2); return (float)h;
}
__device__ __forceinline__ float h16hi(uint32_t u){
  unsigned short s=(unsigned short)(u>>16); _Float16 h; __builtin_memcpy(&h,&s,2); return (float)h;
}
__device__ __forceinline__ float dot2(uint32_t a, uint32_t b, float c){
#if __has_builtin(__builtin_amdgcn_fdot2)
  h2v av,bv; __builtin_memcpy(&av,&a,4); __builtin_memcpy(&bv,&b,4);
  return __builtin_amdgcn_fdot2(av,bv,c,false);
#else
  h2v av,bv; __builtin_memcpy(&av,&a,4); __builtin_memcpy(&bv,&b,4);
  return c + (float)av[0]*(float)bv[0] + (float)av[1]*(float)bv[1];
#endif
}
__device__ __forceinline__ float sigmoidf(float x){ return 1.f/(1.f+__expf(-x)); }
__device__ __forceinline__ float tanh_fast(float x){ float e=__expf(2.f*x); return 1.f - 2.f/(e+1.f); }
__device__ __forceinline__ float wave_sum(float v){
  #pragma unroll
  for(int m=32;m>=1;m>>=1) v += __shfl_xor(v,m,64);
  return v;
}
__device__ __forceinline__ float wave_max(float v){
  #pragma unroll
  for(int m=32;m>=1;m>>=1) v = fmaxf(v,__shfl_xor(v,m,64));
  return v;
}
__device__ __forceinline__ f32x4 mfma16(f16x8 a, f16x8 b, f32x4 c){
  return __builtin_amdgcn_mfma_f32_16x16x32_f16(a, b, c, 0, 0, 0);
}

// ---------- dtype sniffer ----------
__global__ void k_flag(const void* emb_raw, int* flag){
  const unsigned short* u=(const unsigned short*)emb_raw;
  int t=threadIdx.x, found=0;
  for(int i=t;i<2048;i+=256){ float v=bf16_to_f32(u[i]); if(fabsf(v)>8.f) found=1; }
  __shared__ int s;
  if(t==0) s=0;
  __syncthreads();
  if(found) atomicOr(&s,1);
  __syncthreads();
  if(t==0) *flag = s;
}

struct ConvArgs { const void* src[25]; int len[25]; int off[25]; };

__global__ void k_convert(ConvArgs a, const int* __restrict__ flag, float* __restrict__ dst){
  int isf32=*flag;
  int idx=blockIdx.x*256+threadIdx.x;
  #pragma unroll 1
  for(int i=0;i<25;i++){
    if(idx < a.len[i]){
      float v = isf32 ? ((const float*)a.src[i])[idx]
                      : bf16_to_f32(((const unsigned short*)a.src[i])[idx]);
      dst[a.off[i]+idx]=v;
      return;
    }
    idx -= a.len[i];
  }
}

// ---------- prep: Wp B-fragments, pool<64> pairs, transposed mWih, x-gate tables ----------
__global__ void k_prep(const float* __restrict__ cw, unsigned short* __restrict__ wpfrag,
                       uint32_t* __restrict__ wpt2p, float* __restrict__ mWihT,
                       float* __restrict__ xgt){
  int idx=blockIdx.x*256+threadIdx.x;
  if(idx<32768){
    int j=idx&7, lane=(idx>>3)&63, nt=(idx>>9)&7, ks=idx>>12;
    int nl=lane&15, q=lane>>4;
    float v = cw[C_WWP + (nt*16+nl)*256 + ks*32 + q*8 + j];
    wpfrag[idx]=f32_to_h16u(v);
  } else if(idx<49152){
    int i=idx-32768; int kp=i>>7, c=i&127; const float* W=cw+C_PWP;
    wpt2p[i]=pack_h2(W[c*256+2*kp], W[c*256+2*kp+1]);
  } else if(idx<245760){
    int iN=idx-49152; int k=iN/768, g=iN-k*768;
    mWihT[iN] = (g<G3) ? cw[C_MWIH_F + g*256 + k] : cw[C_MWIH_B + (g-G3)*256 + k];
  } else if(idx<442368){
    // x-gate tables: xgt[dir][char][g] = Wih[g]·emb[ch] + bih[g] (+bhh[g] for r/z groups)
    int i=idx-245760;
    int dir=i/98304;
    int r2=i-dir*98304;
    int ch=r2/384, g=r2-ch*384;
    const float* wrow=cw+(dir?C_CWIH_B:C_CWIH_F)+g*EDIM;
    const float* e=cw+C_EMB+ch*EDIM;
    float a=0.f;
    #pragma unroll
    for(int k=0;k<EDIM;k++) a=fmaf(wrow[k],e[k],a);
    a += cw[(dir?C_CBIH_B:C_CBIH_F)+g];
    if(g<256) a += cw[(dir?C_CBHH_B:C_CBHH_F)+g];
    xgt[dir*98304+ch*384+g]=a;
  }
}

// ---------- char BiGRU v3: h-MFMA + table-gathered x-gates, 1 barrier/step ----------
// 16 seqs/block, 8 waves. Wave w owns gate-cols c=16w+nl in each of r/z/n groups;
// x-gates come from the per-char table (L2), prefetched one step ahead.
__global__ __launch_bounds__(512,4) void k_chargru(const int* __restrict__ chars,
    const int* __restrict__ lensp, const float* __restrict__ cw,
    const float* __restrict__ xgt, unsigned short* __restrict__ chout){
  int tid=threadIdx.x;
  int w=tid>>6, L=tid&63, nl=L&15, q=L>>4;
  int dir=blockIdx.y;
  int seq0=blockIdx.x*16;
  const float* Whh=cw+(dir?C_CWHH_B:C_CWHH_F);
  const float* bhh=cw+(dir?C_CBHH_B:C_CBHH_F);
  const float* xg = xgt + dir*98304;

  int c16=w*16+nl;
  f16x8 bh[3][4];
  #pragma unroll
  for(int i=0;i<3;i++){
    int n=(w+8*i)*16+nl;
    const float* wr=Whh + n*HDIM;
    #pragma unroll
    for(int c=0;c<4;c++){
      const float4* p=(const float4*)(wr + c*32 + q*8);
      float4 v0=p[0], v1=p[1];
      f16x8 f;
      f[0]=(_Float16)v0.x; f[1]=(_Float16)v0.y; f[2]=(_Float16)v0.z; f[3]=(_Float16)v0.w;
      f[4]=(_Float16)v1.x; f[5]=(_Float16)v1.y; f[6]=(_Float16)v1.z; f[7]=(_Float16)v1.w;
      bh[i][c]=f;
    }
  }
  float bias_hn=bhh[256+c16];

  __shared__ int cid[16][CLEN];
  __shared__ int lenS[16];
  __shared__ __align__(16) _Float16 hbuf[2][16][136];

  for(int i=tid;i<16*CLEN;i+=512){ int s=i/CLEN, c=i-CLEN*s; cid[s][c]=chars[(seq0+s)*CLEN+c]; }
  if(tid<16) lenS[tid]=lensp[seq0+tid];
  for(int i=tid;i<16*136/2;i+=512) ((uint32_t*)&hbuf[0][0][0])[i]=0u;
  __syncthreads();

  int lenq[4];
  #pragma unroll
  for(int r=0;r<4;r++) lenq[r]=lenS[q*4+r];
  int sw=tid>>5, aw=tid&31;
  int lenp=lenS[sw];

  // preload x-gates for step 0
  float pr[4],pz[4],pn[4];
  {
    int t0 = dir ? CLEN-1 : 0;
    #pragma unroll
    for(int r=0;r<4;r++){
      const float* row=xg + cid[q*4+r][t0]*384 + c16;
      pr[r]=row[0]; pz[r]=row[128]; pn[r]=row[256];
    }
  }
  float hreg[4]={0.f,0.f,0.f,0.f};
  unsigned short* wp = chout + ((size_t)(seq0+sw)*CLEN + (dir?CLEN-1:0))*256 + dir*HDIM + 4*aw;
  int dstep = dir ? -256 : 256;

  for(int step=0; step<CLEN; ++step){
    int t = dir ? CLEN-1-step : step;
    int p = step&1;
    // issue next step's x-gate loads (L2; lands during MFMA+update)
    float qr[4],qz[4],qn[4];
    bool havepf = (step+1 < CLEN);
    if(havepf){
      int tn = dir ? CLEN-2-step : step+1;
      #pragma unroll
      for(int r=0;r<4;r++){
        const float* row=xg + cid[q*4+r][tn]*384 + c16;
        qr[r]=row[0]; qz[r]=row[128]; qn[r]=row[256];
      }
    }
    // ---- MFMA h-part ----
    f32x4 accr={0.f,0.f,0.f,0.f};
    f32x4 accz={0.f,0.f,0.f,0.f};
    f32x4 a2h ={bias_hn,bias_hn,bias_hn,bias_hn};
    const _Float16* hrow=&hbuf[p][nl][0];
    #pragma unroll
    for(int c=0;c<4;c++){
      f16x8 af = *(const f16x8*)(hrow + c*32 + q*8);
      accr=mfma16(af, bh[0][c], accr);
      accz=mfma16(af, bh[1][c], accz);
      a2h =mfma16(af, bh[2][c], a2h);
    }
    // ---- in-register GRU update ----
    #pragma unroll
    for(int r=0;r<4;r++){
      float rg=sigmoidf(accr[r]+pr[r]);
      float zg=sigmoidf(accz[r]+pz[r]);
      float nn=tanh_fast(pn[r] + rg*a2h[r]);
      float hnew=zg*(hreg[r]-nn)+nn;
      bool valid = t < lenq[r];
      float hv = valid ? hnew : hreg[r];
      hreg[r]=hv;
      hbuf[p^1][q*4+r][c16]=(_Float16)hv;
    }
    __syncthreads();
    // ---- coalesced chout writer (reads full rows of new h) ----
    {
      uint2 d=*(const uint2*)&hbuf[p^1][sw][4*aw];
      if(t>=lenp){ d.x=0u; d.y=0u; }
      *(uint2*)wp = d;
      wp += dstep;
    }
    #pragma unroll
    for(int r=0;r<4;r++){ pr[r]=qr[r]; pz[r]=qz[r]; pn[r]=qn[r]; }
  }
}

// ---------- word attention pool via MFMA: one word/block, 4 waves ----------
__global__ __launch_bounds__(256,4) void k_wpool(const unsigned short* __restrict__ chout,
    const unsigned short* __restrict__ wpfrag, const float* __restrict__ bp,
    const float* __restrict__ ctxv, float* __restrict__ words){
  int n=blockIdx.x, tid=threadIdx.x;
  int w=tid>>6, lane=tid&63, nl=lane&15, q=lane>>4;
  __shared__ __align__(16) _Float16 sa[48][264];
  __shared__ float redl[48][4];
  __shared__ float att[48];

  uint4 bfr[2][8];
  const uint4* wp4=(const uint4*)wpfrag;
  #pragma unroll
  for(int ks=0;ks<8;ks++){
    bfr[0][ks]=wp4[(ks*8+2*w  )*64+lane];
    bfr[1][ks]=wp4[(ks*8+2*w+1)*64+lane];
  }
  {
    const uint4* src=(const uint4*)(chout + (size_t)n*48*256);
    #pragma unroll
    for(int i=0;i<6;i++){
      int ii=tid+256*i; int row=ii>>5, c16=ii&31;
      *(uint4*)&sa[row][c16*8]=src[ii];
    }
  }
  __syncthreads();

  f32x4 acc[3][2];
  #pragma unroll
  for(int mt=0;mt<3;mt++){ acc[mt][0]=(f32x4){0,0,0,0}; acc[mt][1]=(f32x4){0,0,0,0}; }
  #pragma unroll
  for(int ks=0;ks<8;ks++){
    f16x8 b0,b1;
    __builtin_memcpy(&b0,&bfr[0][ks],16);
    __builtin_memcpy(&b1,&bfr[1][ks],16);
    #pragma unroll
    for(int mt=0;mt<3;mt++){
      f16x8 af=*(const f16x8*)&sa[mt*16+nl][ks*32+q*8];
      acc[mt][0]=mfma16(af,b0,acc[mt][0]);
      acc[mt][1]=mfma16(af,b1,acc[mt][1]);
    }
  }
  int c0=(2*w)*16+nl, c1=c0+16;
  float bp0=bp[c0], bp1=bp[c1], cv0=ctxv[c0], cv1=ctxv[c1];
  #pragma unroll
  for(int mt=0;mt<3;mt++){
    #pragma unroll
    for(int r=0;r<4;r++){
      float v=tanh_fast(acc[mt][0][r]+bp0)*cv0 + tanh_fast(acc[mt][1][r]+bp1)*cv1;
      v+=__shfl_xor(v,1,64); v+=__shfl_xor(v,2,64);
      v+=__shfl_xor(v,4,64); v+=__shfl_xor(v,8,64);
      if(nl==0) redl[mt*16+q*4+r][w]=v;
    }
  }
  __syncthreads();
  if(tid<64){
    float v=(tid<48)?(redl[tid][0]+redl[tid][1]+redl[tid][2]+redl[tid][3]):-1e30f;
    float mx=wave_max(v);
    float e=(tid<48)?__expf(v-mx):0.f;
    float s=wave_sum(e);
    if(tid<48) att[tid]=e/s;
  }
  __syncthreads();
  float a=0.f;
  #pragma unroll 1
  for(int t=0;t<48;t++) a=fmaf(att[t],(float)sa[t][tid],a);
  words[(size_t)n*256+tid]=a;
}

// ---------- message attention pooling (T=64, fuses final linear) ----------
__global__ __launch_bounds__(256) void k_mpool(const unsigned short* __restrict__ outp,
    const uint32_t* __restrict__ WpT2, const float* __restrict__ bp,
    const float* __restrict__ ctxv,
    const float* __restrict__ Wout, const float* __restrict__ bout,
    void* dout, const int* __restrict__ flag){
  constexpr int T=64; constexpr int NT=T/2;
  int n=blockIdx.x, tid=threadIdx.x;
  __shared__ uint32_t so[T][128];
  __shared__ float red[T][2];
  __shared__ float att[T];
  __shared__ float msgv[256];
  {
    const uint4* src=(const uint4*)(outp + (size_t)n*T*256);
    uint4* d4=(uint4*)&so[0][0];
    #pragma unroll 1
    for(int i=tid;i<T*32;i+=256) d4[i]=src[i];
  }
  __syncthreads();
  int c=tid&127, tt=tid>>7;
  float acc[NT];
  float bpc=bp[c];
  #pragma unroll
  for(int i=0;i<NT;i++) acc[i]=bpc;
  for(int kp=0;kp<128;kp++){
    uint32_t w2=WpT2[kp*128+c];
    #pragma unroll
    for(int i=0;i<NT;i++) acc[i]=dot2(w2, so[2*i+tt][kp], acc[i]);
  }
  float cv=ctxv[c];
  #pragma unroll
  for(int i=0;i<NT;i++){
    float lg=tanh_fast(acc[i])*cv;
    lg=wave_sum(lg);
    if((tid&63)==0) red[2*i+tt][(tid>>6)&1]=lg;
  }
  __syncthreads();
  if(tid<64){
    float v = red[tid][0]+red[tid][1];
    float m = wave_max(v);
    float e = __expf(v-m);
    float s = wave_sum(e);
    att[tid]=e/s;
  }
  __syncthreads();
  if(tid<128){
    float a0=0.f, a1=0.f;
    #pragma unroll 1
    for(int t=0;t<T;t++){
      uint32_t u=so[t][tid];
      float at=att[t];
      a0=fmaf(at,h16lo(u),a0);
      a1=fmaf(at,h16hi(u),a1);
    }
    msgv[2*tid]=a0; msgv[2*tid+1]=a1;
    if(*flag){ float* mo=(float*)dout + 1024 + n*256; mo[2*tid]=a0; mo[2*tid+1]=a1; }
    else { unsigned short* mo=(unsigned short*)dout + 1024 + n*256;
           mo[2*tid]=f32_to_bf16(a0); mo[2*tid+1]=f32_to_bf16(a1); }
  }
  __syncthreads();
  if(tid<OUTD){
    float a=bout[tid];
    #pragma unroll 1
    for(int k=0;k<256;k++) a=fmaf(msgv[k], Wout[tid*256+k], a);
    if(*flag) ((float*)dout)[n*OUTD+tid]=a;
    else ((unsigned short*)dout)[n*OUTD+tid]=f32_to_bf16(a);
  }
}

// ---------- message input-gate GEMM ----------
__global__ __launch_bounds__(256) void k_msgxg(const float* __restrict__ words,
    const float* __restrict__ mWihT, const float* __restrict__ cw, float* __restrict__ xgm){
  int n0=blockIdx.x*16, tid=threadIdx.x;
  __shared__ float wl[16][256];
  #pragma unroll 1
  for(int i=tid;i<16*256;i+=256) ((float*)wl)[i]=words[(size_t)n0*256+i];
  __syncthreads();
  int g0=tid, g1=tid+256, g2=tid+512;
  float b0 = (g0<G3)? cw[C_MBIH_F+g0] : cw[C_MBIH_B+g0-G3];
  float b1 = (g1<G3)? cw[C_MBIH_F+g1] : cw[C_MBIH_B+g1-G3];
  float b2 = (g2<G3)? cw[C_MBIH_F+g2] : cw[C_MBIH_B+g2-G3];
  float a0[16],a1[16],a2[16];
  #pragma unroll
  for(int w=0;w<16;w++){ a0[w]=b0; a1[w]=b1; a2[w]=b2; }
  for(int k=0;k<256;k++){
    float w0=mWihT[k*768+g0], w1=mWihT[k*768+g1], w2v=mWihT[k*768+g2];
    #pragma unroll
    for(int w=0;w<16;w++){
      float x=wl[w][k];
      a0[w]=fmaf(x,w0,a0[w]); a1[w]=fmaf(x,w1,a1[w]); a2[w]=fmaf(x,w2v,a2[w]);
    }
  }
  for(int w=0;w<16;w++){
    int n=n0+w;
    { int g=g0; float v=a0[w]; if(g<G3) xgm[(size_t)n*G3+g]=v; else xgm[(size_t)NW*G3+(size_t)n*G3+g-G3]=v; }
    { int g=g1; float v=a1[w]; if(g<G3) xgm[(size_t)n*G3+g]=v; else xgm[(size_t)NW*G3+(size_t)n*G3+g-G3]=v; }
    { int g=g2; float v=a2[w]; if(g<G3) xgm[(size_t)n*G3+g]=v; else xgm[(size_t)NW*G3+(size_t)n*G3+g-G3]=v; }
  }
}

// ---------- message BiGRU ----------
__global__ __launch_bounds__(384) void k_msggru(const float* __restrict__ cw,
    const float* __restrict__ xgm, unsigned short* __restrict__ msg_out){
  int dir=blockIdx.y, b=blockIdx.x, tid=threadIdx.x;
  const float* Whh=cw+(dir?C_MWHH_B:C_MWHH_F);
  const float* bhh=cw+(dir?C_MBHH_B:C_MBHH_F);
  const float* xg = xgm + (size_t)dir*NW*G3;
  uint32_t whh[64];
  {
    const float4* h4=(const float4*)(Whh + tid*HDIM);
    #pragma unroll
    for(int i=0;i<32;i++){ float4 v=h4[i]; whh[2*i]=pack_h2(v.x,v.y); whh[2*i+1]=pack_h2(v.z,v.w); }
  }
  float bhh_g=bhh[tid];
  __shared__ __align__(16) unsigned short hh[HDIM];
  __shared__ float rr[HDIM], zz[HDIM], xns[HDIM], hns[HDIM];
  if(tid<64) ((uint32_t*)hh)[tid]=0u;
  float hreg=0.f;
  __syncthreads();
  int j=tid&127, gt=tid>>7;
  for(int step=0;step<WRD;step++){
    int w = dir ? (WRD-1-step) : step;
    float xacc = xg[(size_t)(b*WRD+w)*G3 + tid];
    float ha=bhh_g;
    const uint4* hp=(const uint4*)hh;
    #pragma unroll
    for(int q=0;q<16;q++){ uint4 v=hp[q];
      ha=dot2(whh[4*q+0],v.x,ha); ha=dot2(whh[4*q+1],v.y,ha);
      ha=dot2(whh[4*q+2],v.z,ha); ha=dot2(whh[4*q+3],v.w,ha); }
    if(gt==0)      rr[j]=sigmoidf(xacc+ha);
    else if(gt==1) zz[j]=sigmoidf(xacc+ha);
    else { xns[j]=xacc; hns[j]=ha; }
    __syncthreads();
    if(tid<HDIM){
      float r=rr[tid], z=zz[tid];
      float nn=tanh_fast(xns[tid]+r*hns[tid]);
      float hnew=(1.f-z)*nn + z*hreg;
      hreg=hnew;
      hh[tid]=f32_to_h16u(hnew);
      msg_out[(size_t)(b*WRD+w)*256 + dir*HDIM + tid]=f32_to_h16u(hnew);
    }
    __syncthreads();
  }
}

extern "C" void kernel_launch(void* const* d_in, const int* in_sizes, int n_in,
                              void* d_out, int out_size, void* d_ws, size_t ws_size,
                              hipStream_t stream){
  (void)in_sizes; (void)n_in; (void)out_size; (void)ws_size;
  char* ws=(char*)d_ws;
  int* flag=(int*)(ws+OFF_FLAG);
  float* canon=(float*)(ws+OFF_CANON);
  unsigned short* wpfrag=(unsigned short*)(ws+OFF_WPFRAG);
  uint32_t* wpt2p=(uint32_t*)(ws+OFF_WPT2_P);
  float* mWihT=(float*)(ws+OFF_MWIHT);
  float* xgt=(float*)(ws+OFF_XGT);
  float* xgm=(float*)(ws+OFF_XGM);
  float* words=(float*)(ws+OFF_WORDS);
  unsigned short* msgout=(unsigned short*)(ws+OFF_MSGOUT);
  unsigned short* chout=(unsigned short*)(ws+OFF_CHOUT);
  const int* chars=(const int*)d_in[0];
  const int* lensp=(const int*)d_in[1];

  hipLaunchKernelGGL(k_flag, dim3(1), dim3(256), 0, stream, d_in[2], flag);

  ConvArgs ca;
  static const int clen_[25]={16384,24576,49152,384,384,24576,49152,384,384,
                              98304,49152,768,768,98304,49152,768,768,
                              32768,128,128,32768,128,128,2048,8};
  int off=0;
  for(int i=0;i<25;i++){ ca.src[i]=d_in[i+2]; ca.len[i]=clen_[i]; ca.off[i]=off; off+=clen_[i]; }
  hipLaunchKernelGGL(k_convert, dim3((C_TOTAL+255)/256), dim3(256), 0, stream, ca, flag, canon);
  hipLaunchKernelGGL(k_prep, dim3(1728), dim3(256), 0, stream, canon, wpfrag, wpt2p, mWihT, xgt);
  hipLaunchKernelGGL(k_chargru, dim3(NW/16,2), dim3(512), 0, stream, chars, lensp, canon, xgt, chout);
  hipLaunchKernelGGL(k_wpool, dim3(NW), dim3(256), 0, stream, chout, wpfrag,
                     canon+C_WBP, canon+C_WCTX, words);
  hipLaunchKernelGGL(k_msgxg, dim3(NW/16), dim3(256), 0, stream, words, mWihT, canon, xgm);
  hipLaunchKernelGGL(k_msggru, dim3(BATCH,2), dim3(384), 0, stream, canon, xgm, msgout);
  hipLaunchKernelGGL(k_mpool, dim3(BATCH), dim3(256), 0, stream, msgout, wpt2p,
                     canon+C_PBP, canon+C_PCTX,
                     canon+C_WOUT, canon+C_BOUT, d_out, flag);
}

// Round 6
// 522.484 us; speedup vs baseline: 5.4483x; 1.1530x over previous
//
#include <hip/hip_runtime.h>
#include <stdint.h>
#include <stddef.h>

#define NCH   256
#define EDIM  64
#define HDIM  128
#define G3    384
#define BATCH 128
#define WRD   64
#define CLEN  48
#define NW    8192
#define OUTD  8

#define LOG2E 1.44269504088896f

// ---- canonical fp32 weight offsets (element units) ----
#define C_EMB     0
#define C_CWIH_F  16384
#define C_CWHH_F  40960
#define C_CBIH_F  90112
#define C_CBHH_F  90496
#define C_CWIH_B  90880
#define C_CWHH_B  115456
#define C_CBIH_B  164608
#define C_CBHH_B  164992
#define C_MWIH_F  165376
#define C_MWHH_F  263680
#define C_MBIH_F  312832
#define C_MBHH_F  313600
#define C_MWIH_B  314368
#define C_MWHH_B  412672
#define C_MBIH_B  461824
#define C_MBHH_B  462592
#define C_WWP     463360
#define C_WBP     496128
#define C_WCTX    496256
#define C_PWP     496384
#define C_PBP     529152
#define C_PCTX    529280
#define C_WOUT    529408
#define C_BOUT    531456
#define C_TOTAL   531464

// ---- ws byte offsets ----
#define OFF_FLAG    0u
#define OFF_CANON   1024u
#define OFF_WPFRAG  (4u*1024u*1024u)              // 32768 f16 = 65536 B
#define OFF_WPT2_P  (4u*1024u*1024u + 65536u)
#define OFF_MWIHT   (4u*1024u*1024u + 131072u)    // 196608 f32 = 786432 B
#define OFF_XGT4    5111808u                       // 65536 float4 = 1 MB
#define OFF_XGM     (8u*1024u*1024u)
#define OFF_WORDS   35651584u
#define OFF_MSGOUT  47185920u
#define OFF_CHOUT   54525952u

typedef _Float16 h2v __attribute__((ext_vector_type(2)));
typedef _Float16 f16x8 __attribute__((ext_vector_type(8)));
typedef float f32x4 __attribute__((ext_vector_type(4)));

__device__ __forceinline__ float bf16_to_f32(unsigned short u){
  union{unsigned int i;float f;}v; v.i=((unsigned int)u)<<16; return v.f;
}
__device__ __forceinline__ unsigned short f32_to_bf16(float f){
  union{float f;unsigned int i;}v; v.f=f;
  unsigned int u=v.i; unsigned int r=(u + 0x7fffu + ((u>>16)&1u))>>16;
  return (unsigned short)r;
}
__device__ __forceinline__ uint32_t pack_h2(float x,float y){
  h2v h; h[0]=(_Float16)x; h[1]=(_Float16)y; uint32_t u; __builtin_memcpy(&u,&h,4); return u;
}
__device__ __forceinline__ unsigned short f32_to_h16u(float f){
  _Float16 h=(_Float16)f; unsigned short u; __builtin_memcpy(&u,&h,2); return u;
}
__device__ __forceinline__ float h16lo(uint32_t u){
  unsigned short s=(unsigned short)(u&0xffffu); _Float16 h; __builtin_memcpy(&h,&s,2); return (float)h;
}
__device__ __forceinline__ float h16hi(uint32_t u){
  unsigned short s=(unsigned short)(u>>16); _Float16 h; __builtin_memcpy(&h,&s,2); return (float)h;
}
__device__ __forceinline__ float dot2(uint32_t a, uint32_t b, float c){
#if __has_builtin(__builtin_amdgcn_fdot2)
  h2v av,bv; __builtin_memcpy(&av,&a,4); __builtin_memcpy(&bv,&b,4);
  return __builtin_amdgcn_fdot2(av,bv,c,false);
#else
  h2v av,bv; __builtin_memcpy(&av,&a,4); __builtin_memcpy(&bv,&b,4);
  return c + (float)av[0]*(float)bv[0] + (float)av[1]*(float)bv[1];
#endif
}
__device__ __forceinline__ float exp2_fast(float x){
#if __has_builtin(__builtin_amdgcn_exp2f)
  return __builtin_amdgcn_exp2f(x);
#else
  return exp2f(x);
#endif
}
__device__ __forceinline__ float rcp_fast(float x){
#if __has_builtin(__builtin_amdgcn_rcpf)
  return __builtin_amdgcn_rcpf(x);
#else
  return 1.f/x;
#endif
}
// sigmoid(x) given s = -log2e*x
__device__ __forceinline__ float sig2(float s){ return rcp_fast(1.f+exp2_fast(s)); }
// tanh(y) given u = 2*log2e*y
__device__ __forceinline__ float tanh2(float u){ return fmaf(-2.f, rcp_fast(exp2_fast(u)+1.f), 1.f); }
__device__ __forceinline__ float wave_sum(float v){
  #pragma unroll
  for(int m=32;m>=1;m>>=1) v += __shfl_xor(v,m,64);
  return v;
}
__device__ __forceinline__ float wave_max(float v){
  #pragma unroll
  for(int m=32;m>=1;m>>=1) v = fmaxf(v,__shfl_xor(v,m,64));
  return v;
}
__device__ __forceinline__ f32x4 mfma16(f16x8 a, f16x8 b, f32x4 c){
  return __builtin_amdgcn_mfma_f32_16x16x32_f16(a, b, c, 0, 0, 0);
}

struct ConvArgs { const void* src[25]; int len[25]; int off[25]; };

// ---------- convert with inline dtype sniff (block 0 publishes flag for mpool) ----------
__global__ void k_convert(ConvArgs a, int* __restrict__ flag, float* __restrict__ dst){
  const unsigned short* u=(const unsigned short*)a.src[0];  // emb raw
  int found=0;
  for(int i=threadIdx.x;i<2048;i+=256){ float v=bf16_to_f32(u[i]); if(fabsf(v)>8.f) found=1; }
  __shared__ int s;
  if(threadIdx.x==0) s=0;
  __syncthreads();
  if(found) atomicOr(&s,1);
  __syncthreads();
  int isf32=s;
  if(blockIdx.x==0 && threadIdx.x==0) *flag=isf32;
  int idx=blockIdx.x*256+threadIdx.x;
  #pragma unroll 1
  for(int i=0;i<25;i++){
    if(idx < a.len[i]){
      float v = isf32 ? ((const float*)a.src[i])[idx]
                      : bf16_to_f32(((const unsigned short*)a.src[i])[idx]);
      dst[a.off[i]+idx]=v;
      return;
    }
    idx -= a.len[i];
  }
}

// ---------- prep: scaled Wp B-fragments, pool<64> pairs, transposed mWih, x-gate float4 table ----------
__global__ void k_prep(const float* __restrict__ cw, unsigned short* __restrict__ wpfrag,
                       uint32_t* __restrict__ wpt2p, float* __restrict__ mWihT,
                       float4* __restrict__ xgt4){
  int idx=blockIdx.x*256+threadIdx.x;
  if(idx<32768){
    int j=idx&7, lane=(idx>>3)&63, nt=(idx>>9)&7, ks=idx>>12;
    int nl=lane&15, q=lane>>4;
    float v = cw[C_WWP + (nt*16+nl)*256 + ks*32 + q*8 + j] * (2.f*LOG2E);
    wpfrag[idx]=f32_to_h16u(v);
  } else if(idx<49152){
    int i=idx-32768; int kp=i>>7, c=i&127; const float* W=cw+C_PWP;
    wpt2p[i]=pack_h2(W[c*256+2*kp], W[c*256+2*kp+1]);
  } else if(idx<245760){
    int iN=idx-49152; int k=iN/768, g=iN-k*768;
    mWihT[iN] = (g<G3) ? cw[C_MWIH_F + g*256 + k] : cw[C_MWIH_B + (g-G3)*256 + k];
  } else if(idx<311296){
    // x-gate table: {r,z,n} pre-activations per (dir,char,col), pre-scaled for exp2
    int i=idx-245760;
    int dir=i>>15, r2=i&32767, ch=r2>>7, col=r2&127;
    const float* Wih=cw+(dir?C_CWIH_B:C_CWIH_F);
    const float* bih=cw+(dir?C_CBIH_B:C_CBIH_F);
    const float* bhh=cw+(dir?C_CBHH_B:C_CBHH_F);
    const float* e=cw+C_EMB+ch*EDIM;
    float ar=0.f,az=0.f,an=0.f;
    const float* wr=Wih+col*EDIM;
    const float* wz=Wih+(128+col)*EDIM;
    const float* wn=Wih+(256+col)*EDIM;
    #pragma unroll 4
    for(int k=0;k<EDIM;k++){ float ev=e[k]; ar=fmaf(wr[k],ev,ar); az=fmaf(wz[k],ev,az); an=fmaf(wn[k],ev,an); }
    ar=(ar+bih[col]+bhh[col])*(-LOG2E);
    az=(az+bih[128+col]+bhh[128+col])*(-LOG2E);
    an=(an+bih[256+col])*(2.f*LOG2E);
    xgt4[i]=make_float4(ar,az,an,0.f);
  }
}

// ---------- char BiGRU v4: h-MFMA (scaled weights) + float4 x-gate gather, exp2 update ----------
__global__ __launch_bounds__(512,4) void k_chargru(const int* __restrict__ chars,
    const int* __restrict__ lensp, const float* __restrict__ cw,
    const float4* __restrict__ xgt4, unsigned short* __restrict__ chout){
  int tid=threadIdx.x;
  int w=tid>>6, L=tid&63, nl=L&15, q=L>>4;
  int dir=blockIdx.y;
  int seq0=blockIdx.x*16;
  const float* Whh=cw+(dir?C_CWHH_B:C_CWHH_F);
  const float* bhh=cw+(dir?C_CBHH_B:C_CBHH_F);
  const float4* xg4 = xgt4 + (dir<<15);

  int c16=w*16+nl;
  f16x8 bh[3][4];
  const float wsc[3]={-LOG2E,-LOG2E,2.f*LOG2E};
  #pragma unroll
  for(int i=0;i<3;i++){
    int n=(w+8*i)*16+nl;
    const float* wr=Whh + n*HDIM;
    float sc=wsc[i];
    #pragma unroll
    for(int c=0;c<4;c++){
      const float4* p=(const float4*)(wr + c*32 + q*8);
      float4 v0=p[0], v1=p[1];
      f16x8 f;
      f[0]=(_Float16)(v0.x*sc); f[1]=(_Float16)(v0.y*sc); f[2]=(_Float16)(v0.z*sc); f[3]=(_Float16)(v0.w*sc);
      f[4]=(_Float16)(v1.x*sc); f[5]=(_Float16)(v1.y*sc); f[6]=(_Float16)(v1.z*sc); f[7]=(_Float16)(v1.w*sc);
      bh[i][c]=f;
    }
  }
  float bias_hn=bhh[256+c16]*(2.f*LOG2E);

  __shared__ int cidT[CLEN][16];
  __shared__ int lenS[16];
  __shared__ __align__(16) _Float16 hbuf[2][16][136];

  for(int i=tid;i<16*CLEN;i+=512){ int t=i>>4, s=i&15; cidT[t][s]=chars[(seq0+s)*CLEN+t]; }
  if(tid<16) lenS[tid]=lensp[seq0+tid];
  for(int i=tid;i<16*136/2;i+=512) ((uint32_t*)&hbuf[0][0][0])[i]=0u;
  __syncthreads();

  int lenq[4];
  #pragma unroll
  for(int r=0;r<4;r++) lenq[r]=lenS[q*4+r];
  int sw=tid>>5, aw=tid&31;
  int lenp=lenS[sw];

  // preload x-gates for step 0
  float4 pf[4];
  {
    int t0 = dir ? CLEN-1 : 0;
    int4 c4=*(const int4*)&cidT[t0][q*4];
    pf[0]=xg4[c4.x*128+c16]; pf[1]=xg4[c4.y*128+c16];
    pf[2]=xg4[c4.z*128+c16]; pf[3]=xg4[c4.w*128+c16];
  }
  float hreg[4]={0.f,0.f,0.f,0.f};
  unsigned short* wp = chout + ((size_t)(seq0+sw)*CLEN + (dir?CLEN-1:0))*256 + dir*HDIM + 4*aw;
  int dstep = dir ? -256 : 256;

  for(int step=0; step<CLEN; ++step){
    int t = dir ? CLEN-1-step : step;
    int p = step&1;
    // prefetch next step's x-gates (L2; lands during MFMA+update)
    float4 qf[4];
    bool havepf = (step+1 < CLEN);
    if(havepf){
      int tn = dir ? CLEN-2-step : step+1;
      int4 c4=*(const int4*)&cidT[tn][q*4];
      qf[0]=xg4[c4.x*128+c16]; qf[1]=xg4[c4.y*128+c16];
      qf[2]=xg4[c4.z*128+c16]; qf[3]=xg4[c4.w*128+c16];
    }
    // ---- MFMA h-part, split accumulation chains (depth 2) ----
    f32x4 ra={0,0,0,0}, rb={0,0,0,0}, za={0,0,0,0}, zb={0,0,0,0};
    f32x4 ha={bias_hn,bias_hn,bias_hn,bias_hn}, hb={0,0,0,0};
    const _Float16* hrow=&hbuf[p][nl][0];
    f16x8 af0=*(const f16x8*)(hrow + 0*32 + q*8);
    f16x8 af1=*(const f16x8*)(hrow + 1*32 + q*8);
    f16x8 af2=*(const f16x8*)(hrow + 2*32 + q*8);
    f16x8 af3=*(const f16x8*)(hrow + 3*32 + q*8);
    ra=mfma16(af0,bh[0][0],ra); za=mfma16(af0,bh[1][0],za); ha=mfma16(af0,bh[2][0],ha);
    rb=mfma16(af1,bh[0][1],rb); zb=mfma16(af1,bh[1][1],zb); hb=mfma16(af1,bh[2][1],hb);
    ra=mfma16(af2,bh[0][2],ra); za=mfma16(af2,bh[1][2],za); ha=mfma16(af2,bh[2][2],ha);
    rb=mfma16(af3,bh[0][3],rb); zb=mfma16(af3,bh[1][3],zb); hb=mfma16(af3,bh[2][3],hb);
    f32x4 accr=ra+rb, accz=za+zb, a2h=ha+hb;
    // ---- in-register GRU update (exp2/rcp) ----
    #pragma unroll
    for(int r=0;r<4;r++){
      float rg=sig2(accr[r]+pf[r].x);
      float zg=sig2(accz[r]+pf[r].y);
      float nn=tanh2(fmaf(rg,a2h[r],pf[r].z));
      float hnew=fmaf(zg,hreg[r]-nn,nn);
      bool valid = t < lenq[r];
      float hv = valid ? hnew : hreg[r];
      hreg[r]=hv;
      hbuf[p^1][q*4+r][c16]=(_Float16)hv;
    }
    __syncthreads();
    // ---- coalesced chout writer ----
    {
      uint2 d=*(const uint2*)&hbuf[p^1][sw][4*aw];
      if(t>=lenp){ d.x=0u; d.y=0u; }
      *(uint2*)wp = d;
      wp += dstep;
    }
    if(havepf){
      #pragma unroll
      for(int r=0;r<4;r++) pf[r]=qf[r];
    }
  }
}

// ---------- word attention pool via MFMA (Wp pre-scaled by 2log2e) ----------
__global__ __launch_bounds__(256,4) void k_wpool(const unsigned short* __restrict__ chout,
    const unsigned short* __restrict__ wpfrag, const float* __restrict__ bp,
    const float* __restrict__ ctxv, float* __restrict__ words){
  int n=blockIdx.x, tid=threadIdx.x;
  int w=tid>>6, lane=tid&63, nl=lane&15, q=lane>>4;
  __shared__ __align__(16) _Float16 sa[48][264];
  __shared__ float redl[48][4];
  __shared__ float att[48];

  uint4 bfr[2][8];
  const uint4* wp4=(const uint4*)wpfrag;
  #pragma unroll
  for(int ks=0;ks<8;ks++){
    bfr[0][ks]=wp4[(ks*8+2*w  )*64+lane];
    bfr[1][ks]=wp4[(ks*8+2*w+1)*64+lane];
  }
  {
    const uint4* src=(const uint4*)(chout + (size_t)n*48*256);
    #pragma unroll
    for(int i=0;i<6;i++){
      int ii=tid+256*i; int row=ii>>5, c16=ii&31;
      *(uint4*)&sa[row][c16*8]=src[ii];
    }
  }
  __syncthreads();

  f32x4 acc[3][2];
  #pragma unroll
  for(int mt=0;mt<3;mt++){ acc[mt][0]=(f32x4){0,0,0,0}; acc[mt][1]=(f32x4){0,0,0,0}; }
  #pragma unroll
  for(int ks=0;ks<8;ks++){
    f16x8 b0,b1;
    __builtin_memcpy(&b0,&bfr[0][ks],16);
    __builtin_memcpy(&b1,&bfr[1][ks],16);
    #pragma unroll
    for(int mt=0;mt<3;mt++){
      f16x8 af=*(const f16x8*)&sa[mt*16+nl][ks*32+q*8];
      acc[mt][0]=mfma16(af,b0,acc[mt][0]);
      acc[mt][1]=mfma16(af,b1,acc[mt][1]);
    }
  }
  int c0=(2*w)*16+nl, c1=c0+16;
  float bp0=bp[c0]*(2.f*LOG2E), bp1=bp[c1]*(2.f*LOG2E);
  float cv0=ctxv[c0], cv1=ctxv[c1];
  #pragma unroll
  for(int mt=0;mt<3;mt++){
    #pragma unroll
    for(int r=0;r<4;r++){
      float v=tanh2(acc[mt][0][r]+bp0)*cv0 + tanh2(acc[mt][1][r]+bp1)*cv1;
      v+=__shfl_xor(v,1,64); v+=__shfl_xor(v,2,64);
      v+=__shfl_xor(v,4,64); v+=__shfl_xor(v,8,64);
      if(nl==0) redl[mt*16+q*4+r][w]=v;
    }
  }
  __syncthreads();
  if(tid<64){
    float v=(tid<48)?(redl[tid][0]+redl[tid][1]+redl[tid][2]+redl[tid][3]):-1e30f;
    float mx=wave_max(v);
    float e=(tid<48)?exp2_fast((v-mx)*LOG2E):0.f;
    float s=wave_sum(e);
    if(tid<48) att[tid]=e*rcp_fast(s);
  }
  __syncthreads();
  float a=0.f;
  #pragma unroll 1
  for(int t=0;t<48;t++) a=fmaf(att[t],(float)sa[t][tid],a);
  words[(size_t)n*256+tid]=a;
}

// ---------- message attention pooling (T=64, fuses final linear) ----------
__global__ __launch_bounds__(256) void k_mpool(const unsigned short* __restrict__ outp,
    const uint32_t* __restrict__ WpT2, const float* __restrict__ bp,
    const float* __restrict__ ctxv,
    const float* __restrict__ Wout, const float* __restrict__ bout,
    void* dout, const int* __restrict__ flag){
  constexpr int T=64; constexpr int NT=T/2;
  int n=blockIdx.x, tid=threadIdx.x;
  __shared__ uint32_t so[T][128];
  __shared__ float red[T][2];
  __shared__ float att[T];
  __shared__ float msgv[256];
  {
    const uint4* src=(const uint4*)(outp + (size_t)n*T*256);
    uint4* d4=(uint4*)&so[0][0];
    #pragma unroll 1
    for(int i=tid;i<T*32;i+=256) d4[i]=src[i];
  }
  __syncthreads();
  int c=tid&127, tt=tid>>7;
  float acc[NT];
  float bpc=bp[c];
  #pragma unroll
  for(int i=0;i<NT;i++) acc[i]=bpc;
  for(int kp=0;kp<128;kp++){
    uint32_t w2=WpT2[kp*128+c];
    #pragma unroll
    for(int i=0;i<NT;i++) acc[i]=dot2(w2, so[2*i+tt][kp], acc[i]);
  }
  float cv=ctxv[c];
  #pragma unroll
  for(int i=0;i<NT;i++){
    float lg=tanh2(acc[i]*(2.f*LOG2E))*cv;
    lg=wave_sum(lg);
    if((tid&63)==0) red[2*i+tt][(tid>>6)&1]=lg;
  }
  __syncthreads();
  if(tid<64){
    float v = red[tid][0]+red[tid][1];
    float m = wave_max(v);
    float e = exp2_fast((v-m)*LOG2E);
    float s = wave_sum(e);
    att[tid]=e*rcp_fast(s);
  }
  __syncthreads();
  if(tid<128){
    float a0=0.f, a1=0.f;
    #pragma unroll 1
    for(int t=0;t<T;t++){
      uint32_t u=so[t][tid];
      float at=att[t];
      a0=fmaf(at,h16lo(u),a0);
      a1=fmaf(at,h16hi(u),a1);
    }
    msgv[2*tid]=a0; msgv[2*tid+1]=a1;
    if(*flag){ float* mo=(float*)dout + 1024 + n*256; mo[2*tid]=a0; mo[2*tid+1]=a1; }
    else { unsigned short* mo=(unsigned short*)dout + 1024 + n*256;
           mo[2*tid]=f32_to_bf16(a0); mo[2*tid+1]=f32_to_bf16(a1); }
  }
  __syncthreads();
  if(tid<OUTD){
    float a=bout[tid];
    #pragma unroll 1
    for(int k=0;k<256;k++) a=fmaf(msgv[k], Wout[tid*256+k], a);
    if(*flag) ((float*)dout)[n*OUTD+tid]=a;
    else ((unsigned short*)dout)[n*OUTD+tid]=f32_to_bf16(a);
  }
}

// ---------- message input-gate GEMM ----------
__global__ __launch_bounds__(256) void k_msgxg(const float* __restrict__ words,
    const float* __restrict__ mWihT, const float* __restrict__ cw, float* __restrict__ xgm){
  int n0=blockIdx.x*16, tid=threadIdx.x;
  __shared__ float wl[16][256];
  #pragma unroll 1
  for(int i=tid;i<16*256;i+=256) ((float*)wl)[i]=words[(size_t)n0*256+i];
  __syncthreads();
  int g0=tid, g1=tid+256, g2=tid+512;
  float b0 = (g0<G3)? cw[C_MBIH_F+g0] : cw[C_MBIH_B+g0-G3];
  float b1 = (g1<G3)? cw[C_MBIH_F+g1] : cw[C_MBIH_B+g1-G3];
  float b2 = (g2<G3)? cw[C_MBIH_F+g2] : cw[C_MBIH_B+g2-G3];
  float a0[16],a1[16],a2[16];
  #pragma unroll
  for(int w=0;w<16;w++){ a0[w]=b0; a1[w]=b1; a2[w]=b2; }
  for(int k=0;k<256;k++){
    float w0=mWihT[k*768+g0], w1=mWihT[k*768+g1], w2v=mWihT[k*768+g2];
    #pragma unroll
    for(int w=0;w<16;w++){
      float x=wl[w][k];
      a0[w]=fmaf(x,w0,a0[w]); a1[w]=fmaf(x,w1,a1[w]); a2[w]=fmaf(x,w2v,a2[w]);
    }
  }
  for(int w=0;w<16;w++){
    int n=n0+w;
    { int g=g0; float v=a0[w]; if(g<G3) xgm[(size_t)n*G3+g]=v; else xgm[(size_t)NW*G3+(size_t)n*G3+g-G3]=v; }
    { int g=g1; float v=a1[w]; if(g<G3) xgm[(size_t)n*G3+g]=v; else xgm[(size_t)NW*G3+(size_t)n*G3+g-G3]=v; }
    { int g=g2; float v=a2[w]; if(g<G3) xgm[(size_t)n*G3+g]=v; else xgm[(size_t)NW*G3+(size_t)n*G3+g-G3]=v; }
  }
}

// ---------- message BiGRU ----------
__global__ __launch_bounds__(384) void k_msggru(const float* __restrict__ cw,
    const float* __restrict__ xgm, unsigned short* __restrict__ msg_out){
  int dir=blockIdx.y, b=blockIdx.x, tid=threadIdx.x;
  const float* Whh=cw+(dir?C_MWHH_B:C_MWHH_F);
  const float* bhh=cw+(dir?C_MBHH_B:C_MBHH_F);
  const float* xg = xgm + (size_t)dir*NW*G3;
  uint32_t whh[64];
  {
    const float4* h4=(const float4*)(Whh + tid*HDIM);
    #pragma unroll
    for(int i=0;i<32;i++){ float4 v=h4[i]; whh[2*i]=pack_h2(v.x,v.y); whh[2*i+1]=pack_h2(v.z,v.w); }
  }
  float bhh_g=bhh[tid];
  __shared__ __align__(16) unsigned short hh[HDIM];
  __shared__ float rr[HDIM], zz[HDIM], xns[HDIM], hns[HDIM];
  if(tid<64) ((uint32_t*)hh)[tid]=0u;
  float hreg=0.f;
  __syncthreads();
  int j=tid&127, gt=tid>>7;
  for(int step=0;step<WRD;step++){
    int w = dir ? (WRD-1-step) : step;
    float xacc = xg[(size_t)(b*WRD+w)*G3 + tid];
    float ha=bhh_g;
    const uint4* hp=(const uint4*)hh;
    #pragma unroll
    for(int q=0;q<16;q++){ uint4 v=hp[q];
      ha=dot2(whh[4*q+0],v.x,ha); ha=dot2(whh[4*q+1],v.y,ha);
      ha=dot2(whh[4*q+2],v.z,ha); ha=dot2(whh[4*q+3],v.w,ha); }
    if(gt==0)      rr[j]=sig2(-LOG2E*(xacc+ha));
    else if(gt==1) zz[j]=sig2(-LOG2E*(xacc+ha));
    else { xns[j]=xacc; hns[j]=ha; }
    __syncthreads();
    if(tid<HDIM){
      float r=rr[tid], z=zz[tid];
      float nn=tanh2(2.f*LOG2E*(xns[tid]+r*hns[tid]));
      float hnew=(1.f-z)*nn + z*hreg;
      hreg=hnew;
      hh[tid]=f32_to_h16u(hnew);
      msg_out[(size_t)(b*WRD+w)*256 + dir*HDIM + tid]=f32_to_h16u(hnew);
    }
    __syncthreads();
  }
}

extern "C" void kernel_launch(void* const* d_in, const int* in_sizes, int n_in,
                              void* d_out, int out_size, void* d_ws, size_t ws_size,
                              hipStream_t stream){
  (void)in_sizes; (void)n_in; (void)out_size; (void)ws_size;
  char* ws=(char*)d_ws;
  int* flag=(int*)(ws+OFF_FLAG);
  float* canon=(float*)(ws+OFF_CANON);
  unsigned short* wpfrag=(unsigned short*)(ws+OFF_WPFRAG);
  uint32_t* wpt2p=(uint32_t*)(ws+OFF_WPT2_P);
  float* mWihT=(float*)(ws+OFF_MWIHT);
  float4* xgt4=(float4*)(ws+OFF_XGT4);
  float* xgm=(float*)(ws+OFF_XGM);
  float* words=(float*)(ws+OFF_WORDS);
  unsigned short* msgout=(unsigned short*)(ws+OFF_MSGOUT);
  unsigned short* chout=(unsigned short*)(ws+OFF_CHOUT);
  const int* chars=(const int*)d_in[0];
  const int* lensp=(const int*)d_in[1];

  ConvArgs ca;
  static const int clen_[25]={16384,24576,49152,384,384,24576,49152,384,384,
                              98304,49152,768,768,98304,49152,768,768,
                              32768,128,128,32768,128,128,2048,8};
  int off=0;
  for(int i=0;i<25;i++){ ca.src[i]=d_in[i+2]; ca.len[i]=clen_[i]; ca.off[i]=off; off+=clen_[i]; }
  hipLaunchKernelGGL(k_convert, dim3((C_TOTAL+255)/256), dim3(256), 0, stream, ca, flag, canon);
  hipLaunchKernelGGL(k_prep, dim3(1216), dim3(256), 0, stream, canon, wpfrag, wpt2p, mWihT, xgt4);
  hipLaunchKernelGGL(k_chargru, dim3(NW/16,2), dim3(512), 0, stream, chars, lensp, canon, xgt4, chout);
  hipLaunchKernelGGL(k_wpool, dim3(NW), dim3(256), 0, stream, chout, wpfrag,
                     canon+C_WBP, canon+C_WCTX, words);
  hipLaunchKernelGGL(k_msgxg, dim3(NW/16), dim3(256), 0, stream, words, mWihT, canon, xgm);
  hipLaunchKernelGGL(k_msggru, dim3(BATCH,2), dim3(384), 0, stream, canon, xgm, msgout);
  hipLaunchKernelGGL(k_mpool, dim3(BATCH), dim3(256), 0, stream, msgout, wpt2p,
                     canon+C_PBP, canon+C_PCTX,
                     canon+C_WOUT, canon+C_BOUT, d_out, flag);
}

// Round 7
// 406.450 us; speedup vs baseline: 7.0036x; 1.2855x over previous
//
#include <hip/hip_runtime.h>
#include <stdint.h>
#include <stddef.h>

#define NCH   256
#define EDIM  64
#define HDIM  128
#define G3    384
#define BATCH 128
#define WRD   64
#define CLEN  48
#define NW    8192
#define OUTD  8

#define LOG2E 1.44269504088896f

// ---- canonical fp32 weight offsets (element units) ----
#define C_EMB     0
#define C_CWIH_F  16384
#define C_CWHH_F  40960
#define C_CBIH_F  90112
#define C_CBHH_F  90496
#define C_CWIH_B  90880
#define C_CWHH_B  115456
#define C_CBIH_B  164608
#define C_CBHH_B  164992
#define C_MWIH_F  165376
#define C_MWHH_F  263680
#define C_MBIH_F  312832
#define C_MBHH_F  313600
#define C_MWIH_B  314368
#define C_MWHH_B  412672
#define C_MBIH_B  461824
#define C_MBHH_B  462592
#define C_WWP     463360
#define C_WBP     496128
#define C_WCTX    496256
#define C_PWP     496384
#define C_PBP     529152
#define C_PCTX    529280
#define C_WOUT    529408
#define C_BOUT    531456
#define C_TOTAL   531464

// ---- ws byte offsets ----
#define OFF_FLAG    0u
#define OFF_CANON   1024u
#define OFF_WPFRAG  (4u*1024u*1024u)               // 32768 f16 = 64 KB
#define OFF_PFRAG   (4u*1024u*1024u + 65536u)      // 32768 f16 = 64 KB
#define OFF_MFRAG   (4u*1024u*1024u + 131072u)     // 196608 f16 = 384 KB
#define OFF_BIASV   (4u*1024u*1024u + 524288u)     // 768 f32
#define OFF_XGT4    5111808u                        // 65536 float4 = 1 MB
#define OFF_WORDS   35651584u                       // 8192*256 f16 = 4 MB
#define OFF_MSGOUT  47185920u
#define OFF_CHOUT   54525952u

typedef _Float16 h2v __attribute__((ext_vector_type(2)));
typedef _Float16 f16x8 __attribute__((ext_vector_type(8)));
typedef float f32x4 __attribute__((ext_vector_type(4)));

__device__ __forceinline__ float bf16_to_f32(unsigned short u){
  union{unsigned int i;float f;}v; v.i=((unsigned int)u)<<16; return v.f;
}
__device__ __forceinline__ unsigned short f32_to_bf16(float f){
  union{float f;unsigned int i;}v; v.f=f;
  unsigned int u=v.i; unsigned int r=(u + 0x7fffu + ((u>>16)&1u))>>16;
  return (unsigned short)r;
}
__device__ __forceinline__ uint32_t pack_h2(float x,float y){
  h2v h; h[0]=(_Float16)x; h[1]=(_Float16)y; uint32_t u; __builtin_memcpy(&u,&h,4); return u;
}
__device__ __forceinline__ unsigned short f32_to_h16u(float f){
  _Float16 h=(_Float16)f; unsigned short u; __builtin_memcpy(&u,&h,2); return u;
}
__device__ __forceinline__ float dot2(uint32_t a, uint32_t b, float c){
#if __has_builtin(__builtin_amdgcn_fdot2)
  h2v av,bv; __builtin_memcpy(&av,&a,4); __builtin_memcpy(&bv,&b,4);
  return __builtin_amdgcn_fdot2(av,bv,c,false);
#else
  h2v av,bv; __builtin_memcpy(&av,&a,4); __builtin_memcpy(&bv,&b,4);
  return c + (float)av[0]*(float)bv[0] + (float)av[1]*(float)bv[1];
#endif
}
__device__ __forceinline__ float exp2_fast(float x){
#if __has_builtin(__builtin_amdgcn_exp2f)
  return __builtin_amdgcn_exp2f(x);
#else
  return exp2f(x);
#endif
}
__device__ __forceinline__ float rcp_fast(float x){
#if __has_builtin(__builtin_amdgcn_rcpf)
  return __builtin_amdgcn_rcpf(x);
#else
  return 1.f/x;
#endif
}
// sigmoid(x) given s = -log2e*x ; tanh(y) given u = 2*log2e*y
__device__ __forceinline__ float sig2(float s){ return rcp_fast(1.f+exp2_fast(s)); }
__device__ __forceinline__ float tanh2(float u){ return fmaf(-2.f, rcp_fast(exp2_fast(u)+1.f), 1.f); }
__device__ __forceinline__ float wave_sum(float v){
  #pragma unroll
  for(int m=32;m>=1;m>>=1) v += __shfl_xor(v,m,64);
  return v;
}
__device__ __forceinline__ float wave_max(float v){
  #pragma unroll
  for(int m=32;m>=1;m>>=1) v = fmaxf(v,__shfl_xor(v,m,64));
  return v;
}
__device__ __forceinline__ f32x4 mfma16(f16x8 a, f16x8 b, f32x4 c){
  return __builtin_amdgcn_mfma_f32_16x16x32_f16(a, b, c, 0, 0, 0);
}

struct ConvArgs { const void* src[25]; int len[25]; int off[25]; };

// ---------- convert with inline dtype sniff ----------
__global__ void k_convert(ConvArgs a, int* __restrict__ flag, float* __restrict__ dst){
  const unsigned short* u=(const unsigned short*)a.src[0];  // emb raw
  int found=0;
  for(int i=threadIdx.x;i<2048;i+=256){ float v=bf16_to_f32(u[i]); if(fabsf(v)>8.f) found=1; }
  __shared__ int s;
  if(threadIdx.x==0) s=0;
  __syncthreads();
  if(found) atomicOr(&s,1);
  __syncthreads();
  int isf32=s;
  if(blockIdx.x==0 && threadIdx.x==0) *flag=isf32;
  int idx=blockIdx.x*256+threadIdx.x;
  #pragma unroll 1
  for(int i=0;i<25;i++){
    if(idx < a.len[i]){
      float v = isf32 ? ((const float*)a.src[i])[idx]
                      : bf16_to_f32(((const unsigned short*)a.src[i])[idx]);
      dst[a.off[i]+idx]=v;
      return;
    }
    idx -= a.len[i];
  }
}

// ---------- prep: pack wpfrag / pfrag / mfrag / biasv ----------
__global__ void k_prep(const float* __restrict__ cw, unsigned short* __restrict__ wpfrag,
                       unsigned short* __restrict__ pfrag, unsigned short* __restrict__ mfrag,
                       float* __restrict__ biasv){
  int idx=blockIdx.x*256+threadIdx.x;
  if(idx<32768){
    int j=idx&7, lane=(idx>>3)&63, nt=(idx>>9)&7, ks=idx>>12;
    int nl=lane&15, q=lane>>4;
    float v = cw[C_WWP + (nt*16+nl)*256 + ks*32 + q*8 + j] * (2.f*LOG2E);
    wpfrag[idx]=f32_to_h16u(v);
  } else if(idx<65536){
    int i=idx-32768;
    int j=i&7, lane=(i>>3)&63, nt=(i>>9)&7, ks=i>>12;
    int nl=lane&15, q=lane>>4;
    float v = cw[C_PWP + (nt*16+nl)*256 + ks*32 + q*8 + j] * (2.f*LOG2E);
    pfrag[i]=f32_to_h16u(v);
  } else if(idx<262144){
    // mfrag: [ks 8][nt 48][lane 64][j 8]; rows 0..383=mWih_f, 384..767=mWih_b; scaled
    int i=idx-65536;
    int j=i&7, lane=(i>>3)&63, t2=i>>9;
    int nt=t2%48, ks=t2/48;
    int n=nt*16+(lane&15), k=ks*32+(lane>>4)*8+j;
    int gate = (n<G3)? n : n-G3;
    float sc = (gate<256)? -LOG2E : 2.f*LOG2E;
    float v = ((n<G3)? cw[C_MWIH_F + n*256 + k] : cw[C_MWIH_B + (n-G3)*256 + k]) * sc;
    mfrag[i]=f32_to_h16u(v);
  } else if(idx<262912){
    int i=idx-262144;
    int dir=i/384, g=i-384*(i/384);
    float b = cw[(dir?C_MBIH_B:C_MBIH_F)+g] + ((g<256)? cw[(dir?C_MBHH_B:C_MBHH_F)+g] : 0.f);
    biasv[i] = b * ((g<256)? -LOG2E : 2.f*LOG2E);
  }
}

// ---------- prepx: x-gate table via MFMA: xgt[dir][ch][col]={r,z,n,0} pre-scaled ----------
__global__ __launch_bounds__(512) void k_prepx(const float* __restrict__ cw,
                                               float4* __restrict__ xgt4){
  int tid=threadIdx.x;
  int w=tid>>6, L=tid&63, nl=L&15, q=L>>4;
  int mchunk=blockIdx.x, dir=blockIdx.y;
  const float* Wih=cw+(dir?C_CWIH_B:C_CWIH_F);
  const float* bih=cw+(dir?C_CBIH_B:C_CBIH_F);
  const float* bhh=cw+(dir?C_CBHH_B:C_CBHH_F);
  int c16=w*16+nl;

  // B fragments: gate rows {c16, 128+c16, 256+c16}, K=64 (2 k-steps)
  f16x8 bw[3][2];
  #pragma unroll
  for(int i=0;i<3;i++){
    int n=(w+8*i)*16+nl;
    const float* wr=Wih + n*EDIM;
    #pragma unroll
    for(int ks=0;ks<2;ks++){
      const float4* p=(const float4*)(wr + ks*32 + q*8);
      float4 v0=p[0], v1=p[1];
      f16x8 f;
      f[0]=(_Float16)v0.x; f[1]=(_Float16)v0.y; f[2]=(_Float16)v0.z; f[3]=(_Float16)v0.w;
      f[4]=(_Float16)v1.x; f[5]=(_Float16)v1.y; f[6]=(_Float16)v1.z; f[7]=(_Float16)v1.w;
      bw[i][ks]=f;
    }
  }
  float br=bih[c16]+bhh[c16];
  float bz=bih[128+c16]+bhh[128+c16];
  float bn=bih[256+c16];

  #pragma unroll
  for(int mt=0;mt<2;mt++){
    int ch=mchunk*32+mt*16+nl;
    f32x4 ar={0,0,0,0}, az={0,0,0,0}, an={0,0,0,0};
    #pragma unroll
    for(int ks=0;ks<2;ks++){
      const float4* p=(const float4*)(cw + C_EMB + ch*EDIM + ks*32 + q*8);
      float4 v0=p[0], v1=p[1];
      f16x8 a;
      a[0]=(_Float16)v0.x; a[1]=(_Float16)v0.y; a[2]=(_Float16)v0.z; a[3]=(_Float16)v0.w;
      a[4]=(_Float16)v1.x; a[5]=(_Float16)v1.y; a[6]=(_Float16)v1.z; a[7]=(_Float16)v1.w;
      ar=mfma16(a,bw[0][ks],ar); az=mfma16(a,bw[1][ks],az); an=mfma16(a,bw[2][ks],an);
    }
    #pragma unroll
    for(int r=0;r<4;r++){
      int chr=mchunk*32+mt*16+q*4+r;
      xgt4[dir*32768 + chr*128 + c16] =
        make_float4((ar[r]+br)*(-LOG2E), (az[r]+bz)*(-LOG2E), (an[r]+bn)*(2.f*LOG2E), 0.f);
    }
  }
}

// ---------- char BiGRU v4 (unchanged from round 6) ----------
__global__ __launch_bounds__(512,4) void k_chargru(const int* __restrict__ chars,
    const int* __restrict__ lensp, const float* __restrict__ cw,
    const float4* __restrict__ xgt4, unsigned short* __restrict__ chout){
  int tid=threadIdx.x;
  int w=tid>>6, L=tid&63, nl=L&15, q=L>>4;
  int dir=blockIdx.y;
  int seq0=blockIdx.x*16;
  const float* Whh=cw+(dir?C_CWHH_B:C_CWHH_F);
  const float* bhh=cw+(dir?C_CBHH_B:C_CBHH_F);
  const float4* xg4 = xgt4 + (dir<<15);

  int c16=w*16+nl;
  f16x8 bh[3][4];
  const float wsc[3]={-LOG2E,-LOG2E,2.f*LOG2E};
  #pragma unroll
  for(int i=0;i<3;i++){
    int n=(w+8*i)*16+nl;
    const float* wr=Whh + n*HDIM;
    float sc=wsc[i];
    #pragma unroll
    for(int c=0;c<4;c++){
      const float4* p=(const float4*)(wr + c*32 + q*8);
      float4 v0=p[0], v1=p[1];
      f16x8 f;
      f[0]=(_Float16)(v0.x*sc); f[1]=(_Float16)(v0.y*sc); f[2]=(_Float16)(v0.z*sc); f[3]=(_Float16)(v0.w*sc);
      f[4]=(_Float16)(v1.x*sc); f[5]=(_Float16)(v1.y*sc); f[6]=(_Float16)(v1.z*sc); f[7]=(_Float16)(v1.w*sc);
      bh[i][c]=f;
    }
  }
  float bias_hn=bhh[256+c16]*(2.f*LOG2E);

  __shared__ int cidT[CLEN][16];
  __shared__ int lenS[16];
  __shared__ __align__(16) _Float16 hbuf[2][16][136];

  for(int i=tid;i<16*CLEN;i+=512){ int t=i>>4, s=i&15; cidT[t][s]=chars[(seq0+s)*CLEN+t]; }
  if(tid<16) lenS[tid]=lensp[seq0+tid];
  for(int i=tid;i<16*136/2;i+=512) ((uint32_t*)&hbuf[0][0][0])[i]=0u;
  __syncthreads();

  int lenq[4];
  #pragma unroll
  for(int r=0;r<4;r++) lenq[r]=lenS[q*4+r];
  int sw=tid>>5, aw=tid&31;
  int lenp=lenS[sw];

  float4 pf[4];
  {
    int t0 = dir ? CLEN-1 : 0;
    int4 c4=*(const int4*)&cidT[t0][q*4];
    pf[0]=xg4[c4.x*128+c16]; pf[1]=xg4[c4.y*128+c16];
    pf[2]=xg4[c4.z*128+c16]; pf[3]=xg4[c4.w*128+c16];
  }
  float hreg[4]={0.f,0.f,0.f,0.f};
  unsigned short* wp = chout + ((size_t)(seq0+sw)*CLEN + (dir?CLEN-1:0))*256 + dir*HDIM + 4*aw;
  int dstep = dir ? -256 : 256;

  for(int step=0; step<CLEN; ++step){
    int t = dir ? CLEN-1-step : step;
    int p = step&1;
    float4 qf[4];
    bool havepf = (step+1 < CLEN);
    if(havepf){
      int tn = dir ? CLEN-2-step : step+1;
      int4 c4=*(const int4*)&cidT[tn][q*4];
      qf[0]=xg4[c4.x*128+c16]; qf[1]=xg4[c4.y*128+c16];
      qf[2]=xg4[c4.z*128+c16]; qf[3]=xg4[c4.w*128+c16];
    }
    f32x4 ra={0,0,0,0}, rb={0,0,0,0}, za={0,0,0,0}, zb={0,0,0,0};
    f32x4 ha={bias_hn,bias_hn,bias_hn,bias_hn}, hb={0,0,0,0};
    const _Float16* hrow=&hbuf[p][nl][0];
    f16x8 af0=*(const f16x8*)(hrow + 0*32 + q*8);
    f16x8 af1=*(const f16x8*)(hrow + 1*32 + q*8);
    f16x8 af2=*(const f16x8*)(hrow + 2*32 + q*8);
    f16x8 af3=*(const f16x8*)(hrow + 3*32 + q*8);
    ra=mfma16(af0,bh[0][0],ra); za=mfma16(af0,bh[1][0],za); ha=mfma16(af0,bh[2][0],ha);
    rb=mfma16(af1,bh[0][1],rb); zb=mfma16(af1,bh[1][1],zb); hb=mfma16(af1,bh[2][1],hb);
    ra=mfma16(af2,bh[0][2],ra); za=mfma16(af2,bh[1][2],za); ha=mfma16(af2,bh[2][2],ha);
    rb=mfma16(af3,bh[0][3],rb); zb=mfma16(af3,bh[1][3],zb); hb=mfma16(af3,bh[2][3],hb);
    f32x4 accr=ra+rb, accz=za+zb, a2h=ha+hb;
    #pragma unroll
    for(int r=0;r<4;r++){
      float rg=sig2(accr[r]+pf[r].x);
      float zg=sig2(accz[r]+pf[r].y);
      float nn=tanh2(fmaf(rg,a2h[r],pf[r].z));
      float hnew=fmaf(zg,hreg[r]-nn,nn);
      bool valid = t < lenq[r];
      float hv = valid ? hnew : hreg[r];
      hreg[r]=hv;
      hbuf[p^1][q*4+r][c16]=(_Float16)hv;
    }
    __syncthreads();
    {
      uint2 d=*(const uint2*)&hbuf[p^1][sw][4*aw];
      if(t>=lenp){ d.x=0u; d.y=0u; }
      *(uint2*)wp = d;
      wp += dstep;
    }
    if(havepf){
      #pragma unroll
      for(int r=0;r<4;r++) pf[r]=qf[r];
    }
  }
}

// ---------- word attention pool via MFMA; words output f16 ----------
__global__ __launch_bounds__(256,4) void k_wpool(const unsigned short* __restrict__ chout,
    const unsigned short* __restrict__ wpfrag, const float* __restrict__ bp,
    const float* __restrict__ ctxv, _Float16* __restrict__ wordsF16){
  int n=blockIdx.x, tid=threadIdx.x;
  int w=tid>>6, lane=tid&63, nl=lane&15, q=lane>>4;
  __shared__ __align__(16) _Float16 sa[48][264];
  __shared__ float redl[48][4];
  __shared__ float att[48];

  uint4 bfr[2][8];
  const uint4* wp4=(const uint4*)wpfrag;
  #pragma unroll
  for(int ks=0;ks<8;ks++){
    bfr[0][ks]=wp4[(ks*8+2*w  )*64+lane];
    bfr[1][ks]=wp4[(ks*8+2*w+1)*64+lane];
  }
  {
    const uint4* src=(const uint4*)(chout + (size_t)n*48*256);
    #pragma unroll
    for(int i=0;i<6;i++){
      int ii=tid+256*i; int row=ii>>5, c16=ii&31;
      *(uint4*)&sa[row][c16*8]=src[ii];
    }
  }
  __syncthreads();

  f32x4 acc[3][2];
  #pragma unroll
  for(int mt=0;mt<3;mt++){ acc[mt][0]=(f32x4){0,0,0,0}; acc[mt][1]=(f32x4){0,0,0,0}; }
  #pragma unroll
  for(int ks=0;ks<8;ks++){
    f16x8 b0,b1;
    __builtin_memcpy(&b0,&bfr[0][ks],16);
    __builtin_memcpy(&b1,&bfr[1][ks],16);
    #pragma unroll
    for(int mt=0;mt<3;mt++){
      f16x8 af=*(const f16x8*)&sa[mt*16+nl][ks*32+q*8];
      acc[mt][0]=mfma16(af,b0,acc[mt][0]);
      acc[mt][1]=mfma16(af,b1,acc[mt][1]);
    }
  }
  int c0=(2*w)*16+nl, c1=c0+16;
  float bp0=bp[c0]*(2.f*LOG2E), bp1=bp[c1]*(2.f*LOG2E);
  float cv0=ctxv[c0], cv1=ctxv[c1];
  #pragma unroll
  for(int mt=0;mt<3;mt++){
    #pragma unroll
    for(int r=0;r<4;r++){
      float v=tanh2(acc[mt][0][r]+bp0)*cv0 + tanh2(acc[mt][1][r]+bp1)*cv1;
      v+=__shfl_xor(v,1,64); v+=__shfl_xor(v,2,64);
      v+=__shfl_xor(v,4,64); v+=__shfl_xor(v,8,64);
      if(nl==0) redl[mt*16+q*4+r][w]=v;
    }
  }
  __syncthreads();
  if(tid<64){
    float v=(tid<48)?(redl[tid][0]+redl[tid][1]+redl[tid][2]+redl[tid][3]):-1e30f;
    float mx=wave_max(v);
    float e=(tid<48)?exp2_fast((v-mx)*LOG2E):0.f;
    float s=wave_sum(e);
    if(tid<48) att[tid]=e*rcp_fast(s);
  }
  __syncthreads();
  float a=0.f;
  #pragma unroll 1
  for(int t=0;t<48;t++) a=fmaf(att[t],(float)sa[t][tid],a);
  wordsF16[(size_t)n*256+tid]=(_Float16)a;
}

// ---------- fused message GRU: MFMA xg-GEMM prologue + recurrent loop ----------
__global__ __launch_bounds__(384) void k_msggru(const float* __restrict__ cw,
    const _Float16* __restrict__ wordsF16, const unsigned short* __restrict__ mfrag,
    const float* __restrict__ biasv, unsigned short* __restrict__ msg_out){
  int dir=blockIdx.y, b=blockIdx.x, tid=threadIdx.x;
  int w=tid>>6, lane=tid&63, nl=lane&15, q=lane>>4;

  __shared__ _Float16 xgL[64][392];                 // 50 KB: pre-scaled gate pre-acts
  __shared__ __align__(16) _Float16 hh[HDIM];
  __shared__ float rr[HDIM], zz[HDIM], xns[HDIM], hns[HDIM];

  // ---- phase 1: xg[64][384] = words[b][64][256] @ mWih^T (MFMA, scaled frags) ----
  {
    int ntb = dir*24 + w*4;
    const uint4* mf4=(const uint4*)mfrag;
    const uint4* wv=(const uint4*)wordsF16;
    f32x4 acc[4][4];
    #pragma unroll
    for(int mt=0;mt<4;mt++)
      #pragma unroll
      for(int i=0;i<4;i++) acc[mt][i]=(f32x4){0,0,0,0};
    #pragma unroll
    for(int ks=0;ks<8;ks++){
      f16x8 bf[4];
      #pragma unroll
      for(int i=0;i<4;i++){
        uint4 u=mf4[((ks*48 + ntb+i)*64 + lane)];
        __builtin_memcpy(&bf[i],&u,16);
      }
      #pragma unroll
      for(int mt=0;mt<4;mt++){
        uint4 u=wv[((size_t)b*64 + mt*16 + nl)*32 + ks*4 + q];
        f16x8 av; __builtin_memcpy(&av,&u,16);
        #pragma unroll
        for(int i=0;i<4;i++) acc[mt][i]=mfma16(av,bf[i],acc[mt][i]);
      }
    }
    float bi[4];
    #pragma unroll
    for(int i=0;i<4;i++) bi[i]=biasv[dir*384 + (w*4+i)*16+nl];
    #pragma unroll
    for(int mt=0;mt<4;mt++)
      #pragma unroll
      for(int i=0;i<4;i++){
        int g=(w*4+i)*16+nl;
        #pragma unroll
        for(int r=0;r<4;r++)
          xgL[mt*16+q*4+r][g]=(_Float16)(acc[mt][i][r]+bi[i]);
      }
  }

  // ---- phase 2: recurrent loop (pre-scaled whh) ----
  const float* Whh=cw+(dir?C_MWHH_B:C_MWHH_F);
  const float* bhh=cw+(dir?C_MBHH_B:C_MBHH_F);
  uint32_t whh[64];
  {
    float sc = (tid<256) ? -LOG2E : 2.f*LOG2E;
    const float4* h4=(const float4*)(Whh + tid*HDIM);
    #pragma unroll
    for(int i=0;i<32;i++){ float4 v=h4[i]; whh[2*i]=pack_h2(v.x*sc,v.y*sc); whh[2*i+1]=pack_h2(v.z*sc,v.w*sc); }
  }
  float ha0 = (tid>=256) ? bhh[tid]*(2.f*LOG2E) : 0.f;
  if(tid<64) ((uint32_t*)hh)[tid]=0u;
  float hreg=0.f;
  __syncthreads();
  int j=tid&127, gt=tid>>7;
  for(int step=0;step<WRD;step++){
    int wt = dir ? (WRD-1-step) : step;
    float xacc = (float)xgL[wt][tid];
    float ha=ha0;
    const uint4* hp=(const uint4*)hh;
    #pragma unroll
    for(int qq=0;qq<16;qq++){ uint4 v=hp[qq];
      ha=dot2(whh[4*qq+0],v.x,ha); ha=dot2(whh[4*qq+1],v.y,ha);
      ha=dot2(whh[4*qq+2],v.z,ha); ha=dot2(whh[4*qq+3],v.w,ha); }
    if(gt==0)      rr[j]=sig2(xacc+ha);
    else if(gt==1) zz[j]=sig2(xacc+ha);
    else { xns[j]=xacc; hns[j]=ha; }
    __syncthreads();
    if(tid<HDIM){
      float r=rr[tid], z=zz[tid];
      float nn=tanh2(fmaf(r,hns[tid],xns[tid]));
      float hnew=fmaf(z,hreg-nn,nn);
      hreg=hnew;
      hh[tid]=(_Float16)hnew;
      msg_out[(size_t)(b*WRD+wt)*256 + dir*HDIM + tid]=f32_to_h16u(hnew);
    }
    __syncthreads();
  }
}

// ---------- message attention pool via MFMA + fused final linear ----------
__global__ __launch_bounds__(256) void k_mpool(const unsigned short* __restrict__ outp,
    const unsigned short* __restrict__ pfrag, const float* __restrict__ bp,
    const float* __restrict__ ctxv,
    const float* __restrict__ Wout, const float* __restrict__ bout,
    void* dout, const int* __restrict__ flag){
  int n=blockIdx.x, tid=threadIdx.x;
  int w=tid>>6, lane=tid&63, nl=lane&15, q=lane>>4;
  __shared__ __align__(16) _Float16 sa[64][264];
  __shared__ float redl[64][4];
  __shared__ float att[64];
  __shared__ float msgv[256];

  uint4 bfr[2][8];
  const uint4* pf4=(const uint4*)pfrag;
  #pragma unroll
  for(int ks=0;ks<8;ks++){
    bfr[0][ks]=pf4[(ks*8+2*w  )*64+lane];
    bfr[1][ks]=pf4[(ks*8+2*w+1)*64+lane];
  }
  {
    const uint4* src=(const uint4*)(outp + (size_t)n*64*256);
    #pragma unroll
    for(int i=0;i<8;i++){
      int ii=tid+256*i; int row=ii>>5, c16=ii&31;
      *(uint4*)&sa[row][c16*8]=src[ii];
    }
  }
  __syncthreads();

  f32x4 acc[4][2];
  #pragma unroll
  for(int mt=0;mt<4;mt++){ acc[mt][0]=(f32x4){0,0,0,0}; acc[mt][1]=(f32x4){0,0,0,0}; }
  #pragma unroll
  for(int ks=0;ks<8;ks++){
    f16x8 b0,b1;
    __builtin_memcpy(&b0,&bfr[0][ks],16);
    __builtin_memcpy(&b1,&bfr[1][ks],16);
    #pragma unroll
    for(int mt=0;mt<4;mt++){
      f16x8 af=*(const f16x8*)&sa[mt*16+nl][ks*32+q*8];
      acc[mt][0]=mfma16(af,b0,acc[mt][0]);
      acc[mt][1]=mfma16(af,b1,acc[mt][1]);
    }
  }
  int c0=(2*w)*16+nl, c1=c0+16;
  float bp0=bp[c0]*(2.f*LOG2E), bp1=bp[c1]*(2.f*LOG2E);
  float cv0=ctxv[c0], cv1=ctxv[c1];
  #pragma unroll
  for(int mt=0;mt<4;mt++){
    #pragma unroll
    for(int r=0;r<4;r++){
      float v=tanh2(acc[mt][0][r]+bp0)*cv0 + tanh2(acc[mt][1][r]+bp1)*cv1;
      v+=__shfl_xor(v,1,64); v+=__shfl_xor(v,2,64);
      v+=__shfl_xor(v,4,64); v+=__shfl_xor(v,8,64);
      if(nl==0) redl[mt*16+q*4+r][w]=v;
    }
  }
  __syncthreads();
  if(tid<64){
    float v=redl[tid][0]+redl[tid][1]+redl[tid][2]+redl[tid][3];
    float mx=wave_max(v);
    float e=exp2_fast((v-mx)*LOG2E);
    float s=wave_sum(e);
    att[tid]=e*rcp_fast(s);
  }
  __syncthreads();
  float a=0.f;
  #pragma unroll 1
  for(int t=0;t<64;t++) a=fmaf(att[t],(float)sa[t][tid],a);
  msgv[tid]=a;
  if(*flag){ ((float*)dout)[1024 + n*256 + tid]=a; }
  else { ((unsigned short*)dout)[1024 + n*256 + tid]=f32_to_bf16(a); }
  __syncthreads();
  if(tid<OUTD){
    float acc2=bout[tid];
    #pragma unroll 1
    for(int k=0;k<256;k++) acc2=fmaf(msgv[k], Wout[tid*256+k], acc2);
    if(*flag) ((float*)dout)[n*OUTD+tid]=acc2;
    else ((unsigned short*)dout)[n*OUTD+tid]=f32_to_bf16(acc2);
  }
}

extern "C" void kernel_launch(void* const* d_in, const int* in_sizes, int n_in,
                              void* d_out, int out_size, void* d_ws, size_t ws_size,
                              hipStream_t stream){
  (void)in_sizes; (void)n_in; (void)out_size; (void)ws_size;
  char* ws=(char*)d_ws;
  int* flag=(int*)(ws+OFF_FLAG);
  float* canon=(float*)(ws+OFF_CANON);
  unsigned short* wpfrag=(unsigned short*)(ws+OFF_WPFRAG);
  unsigned short* pfrag=(unsigned short*)(ws+OFF_PFRAG);
  unsigned short* mfrag=(unsigned short*)(ws+OFF_MFRAG);
  float* biasv=(float*)(ws+OFF_BIASV);
  float4* xgt4=(float4*)(ws+OFF_XGT4);
  _Float16* wordsF16=(_Float16*)(ws+OFF_WORDS);
  unsigned short* msgout=(unsigned short*)(ws+OFF_MSGOUT);
  unsigned short* chout=(unsigned short*)(ws+OFF_CHOUT);
  const int* chars=(const int*)d_in[0];
  const int* lensp=(const int*)d_in[1];

  ConvArgs ca;
  static const int clen_[25]={16384,24576,49152,384,384,24576,49152,384,384,
                              98304,49152,768,768,98304,49152,768,768,
                              32768,128,128,32768,128,128,2048,8};
  int off=0;
  for(int i=0;i<25;i++){ ca.src[i]=d_in[i+2]; ca.len[i]=clen_[i]; ca.off[i]=off; off+=clen_[i]; }
  hipLaunchKernelGGL(k_convert, dim3((C_TOTAL+255)/256), dim3(256), 0, stream, ca, flag, canon);
  hipLaunchKernelGGL(k_prep, dim3(1028), dim3(256), 0, stream, canon, wpfrag, pfrag, mfrag, biasv);
  hipLaunchKernelGGL(k_prepx, dim3(8,2), dim3(512), 0, stream, canon, xgt4);
  hipLaunchKernelGGL(k_chargru, dim3(NW/16,2), dim3(512), 0, stream, chars, lensp, canon, xgt4, chout);
  hipLaunchKernelGGL(k_wpool, dim3(NW), dim3(256), 0, stream, chout, wpfrag,
                     canon+C_WBP, canon+C_WCTX, wordsF16);
  hipLaunchKernelGGL(k_msggru, dim3(BATCH,2), dim3(384), 0, stream, canon, wordsF16, mfrag, biasv, msgout);
  hipLaunchKernelGGL(k_mpool, dim3(BATCH), dim3(256), 0, stream, msgout, pfrag,
                     canon+C_PBP, canon+C_PCTX,
                     canon+C_WOUT, canon+C_BOUT, d_out, flag);
}